// Round 10
// baseline (197.687 us; speedup 1.0000x reference)
//
#include <hip/hip_runtime.h>
#include <hip/hip_bf16.h>

#define HIDDEN 1024
#define NHEAD 16
#define NKV 4
#define HDIM 64
#define KVDIM 256
#define SEQ 2048
#define BATCH 2
#define NQKV 1536   // 1024 (Q) + 256 (K) + 256 (V)

typedef __attribute__((ext_vector_type(4)))  float f32x4;
typedef __attribute__((ext_vector_type(16))) float f32x16;
typedef __attribute__((ext_vector_type(8)))  short s16x8;
typedef __attribute__((ext_vector_type(4)))  short s16x4;

#if defined(__has_builtin)
#if __has_builtin(__builtin_amdgcn_exp2f)
#define EXP2F(x) __builtin_amdgcn_exp2f(x)
#else
#define EXP2F(x) exp2f(x)
#endif
#else
#define EXP2F(x) exp2f(x)
#endif

static __device__ __forceinline__ ushort f2bf(float f) {
    union { __hip_bfloat16 b; ushort u; } cv; cv.b = __float2bfloat16(f); return cv.u;
}
// Packed round-half-up f32x2 -> bf16x2 in 3 VALU ops. R8 PROVED raw
// v_cvt_pk_bf16_f32 truncates (biased P -> FAIL); +0x8000 integer-domain
// pre-add restores round-half-up. R9: passes, absmax 4.88e-4 (2.2x margin).
static __device__ __forceinline__ unsigned cvtpk2_rhu(float a, float b) {
    float ah = __uint_as_float(__float_as_uint(a) + 0x8000u);
    float bh = __uint_as_float(__float_as_uint(b) + 0x8000u);
    unsigned r;
    asm("v_cvt_pk_bf16_f32 %0, %1, %2" : "=v"(r) : "v"(ah), "v"(bh));
    return r;
}
// v_permlane32_swap_b32 a, b: exchanges a's high-32 lanes with b's low-32
// lanes (lane i <-> i+32, same q=n32 row). Both registers are modified and
// both results are used (T12 pattern).
static __device__ __forceinline__ void plane32_swap(unsigned& a, unsigned& b) {
    asm("v_permlane32_swap_b32 %0, %1" : "+v"(a), "+v"(b));
}
// async global->LDS, 16B per lane. LDS dest = wave-uniform base + lane*16.
static __device__ __forceinline__ void async16(const void* g, void* l) {
    __builtin_amdgcn_global_load_lds((__attribute__((address_space(1))) void*)g,
                                     (__attribute__((address_space(3))) void*)l, 16, 0, 0);
}

// ---------------------------------------------------------------------------
// Fused prep: grid [0,4096) = X fp32->bf16; [4096,4480) = Wq/Wk/Wv transpose;
// [4480,4736) = Wo transpose. One dispatch instead of three.
// ---------------------------------------------------------------------------
__global__ __launch_bounds__(256)
void prep(const float* __restrict__ X, ushort* __restrict__ Xb,
          const float* __restrict__ Wq, const float* __restrict__ Wk,
          const float* __restrict__ Wv, ushort* __restrict__ Tqkv,
          const float* __restrict__ Wo, ushort* __restrict__ Two)
{
    __shared__ float Tl[64][65];
    const int bid = blockIdx.x, tid = threadIdx.x;

    if (bid < 4096) {           // ---- cvt_x: 4096 blocks x 256 thr x float4
        int i = bid * 256 + tid;
        float4 v = ((const float4*)X)[i];
        ushort4 o;
        o.x = f2bf(v.x); o.y = f2bf(v.y); o.z = f2bf(v.z); o.w = f2bf(v.w);
        ((ushort4*)Xb)[i] = o;
        return;
    }

    const float* W; ushort* T; int N, n0, k0, roff;
    if (bid < 4096 + 384) {     // ---- wtrans_qkv (24 x 16)
        int wq = bid - 4096;
        int bx = wq % 24; k0 = (wq / 24) * 64;
        T = Tqkv;
        if (bx < 16)      { W = Wq; N = 1024; n0 = bx * 64;        roff = 0; }
        else if (bx < 20) { W = Wk; N = 256;  n0 = (bx - 16) * 64; roff = 1024; }
        else              { W = Wv; N = 256;  n0 = (bx - 20) * 64; roff = 1280; }
    } else {                    // ---- wtrans_one (Wo, 16 x 16)
        int wo = bid - 4480;
        int bx = wo % 16; k0 = (wo / 16) * 64;
        W = Wo; T = Two; N = 1024; n0 = bx * 64; roff = 0;
    }

#pragma unroll
    for (int it = 0; it < 4; it++) {
        int idx = tid + it * 256;
        int kk = idx >> 4, n4 = (idx & 15) * 4;
        float4 v = *(const float4*)(W + (size_t)(k0 + kk) * N + n0 + n4);
        Tl[kk][n4 + 0] = v.x; Tl[kk][n4 + 1] = v.y;
        Tl[kk][n4 + 2] = v.z; Tl[kk][n4 + 3] = v.w;
    }
    __syncthreads();
#pragma unroll
    for (int it = 0; it < 4; it++) {
        int idx = tid + it * 256;
        int n = idx >> 4, k4 = (idx & 15) * 4;
        ushort4 h4;
        h4.x = f2bf(Tl[k4 + 0][n]); h4.y = f2bf(Tl[k4 + 1][n]);
        h4.z = f2bf(Tl[k4 + 2][n]); h4.w = f2bf(Tl[k4 + 3][n]);
        *(ushort4*)(T + (size_t)(roff + n0 + n) * HIDDEN + k0 + k4) = h4;
    }
}

// ---------------------------------------------------------------------------
// Plain-bf16 MFMA GEMM, fp32 accumulate: C = A[M,K] @ B^T[N,K] + bias.
// m97 geometry (verified ladder: 874-912 TF at 4096^3): 128x128 tile, BK=32,
// 4 waves 2x2, each wave a 64x64 sub-tile (16 MFMA per wave per K-step),
// staging via 4x global_load_lds width-16/thread.
// MODE 0: bf16 out (Q cols scaled 0.125*log2e). MODE 1: fp32 out.
// ---------------------------------------------------------------------------
template <int MODE>
__global__ __launch_bounds__(256)
void gemm_bf(const ushort* __restrict__ A, const ushort* __restrict__ Bt,
             const float* __restrict__ b0, const float* __restrict__ b1,
             const float* __restrict__ b2, void* __restrict__ Cout,
             int M, int N, int K)
{
    __shared__ __align__(16) ushort Ah[128 * 32];
    __shared__ __align__(16) ushort Bh[128 * 32];

    const int tid = threadIdx.x;
    const int lane = tid & 63, wv = tid >> 6;
    const int wr = wv >> 1, wc = wv & 1;
    const int m = lane & 15, c = lane >> 4;
    const int row0 = blockIdx.y * 128, col0 = blockIdx.x * 128;

    const ushort* gA[2]; const ushort* gB[2]; int ldsO[2];
#pragma unroll
    for (int it = 0; it < 2; it++) {
        int idx = it * 256 + tid;
        gA[it] = A  + (size_t)(row0 + (idx >> 2)) * K + (idx & 3) * 8;
        gB[it] = Bt + (size_t)(col0 + (idx >> 2)) * K + (idx & 3) * 8;
        ldsO[it] = idx * 8;
    }

    f32x4 acc[4][4];
#pragma unroll
    for (int t = 0; t < 4; t++)
#pragma unroll
        for (int u = 0; u < 4; u++) acc[t][u] = (f32x4){0.f, 0.f, 0.f, 0.f};

    for (int k0 = 0; k0 < K; k0 += 32) {
        __syncthreads();
#pragma unroll
        for (int it = 0; it < 2; it++) {
            async16(gA[it] + k0, Ah + ldsO[it]);
            async16(gB[it] + k0, Bh + ldsO[it]);
        }
        __syncthreads();   // compiler drains vmcnt before s_barrier

        s16x8 ah[4], bh[4];
#pragma unroll
        for (int t = 0; t < 4; t++)
            ah[t] = *(const s16x8*)&Ah[(wr * 64 + t * 16 + m) * 32 + c * 8];
#pragma unroll
        for (int u = 0; u < 4; u++)
            bh[u] = *(const s16x8*)&Bh[(wc * 64 + u * 16 + m) * 32 + c * 8];
#pragma unroll
        for (int t = 0; t < 4; t++)
#pragma unroll
            for (int u = 0; u < 4; u++)
                acc[t][u] = __builtin_amdgcn_mfma_f32_16x16x32_bf16(ah[t], bh[u], acc[t][u], 0, 0, 0);
    }

    const int orow = row0 + wr * 64 + 4 * c;   // + 16t + r
    const int ocol = col0 + wc * 64 + m;       // + 16u
    if (MODE == 0) {
        ushort* Cb = (ushort*)Cout;
#pragma unroll
        for (int u = 0; u < 4; u++) {
            int n = ocol + 16 * u;
            float bias, scl;
            if (n < 1024)      { bias = b0[n];        scl = 0.18033688f; }  // 0.125*log2(e)
            else if (n < 1280) { bias = b1[n - 1024]; scl = 1.0f; }
            else               { bias = b2[n - 1280]; scl = 1.0f; }
#pragma unroll
            for (int t = 0; t < 4; t++)
#pragma unroll
                for (int r = 0; r < 4; r++)
                    Cb[(size_t)(orow + 16 * t + r) * N + n] = f2bf((acc[t][u][r] + bias) * scl);
        }
    } else {
        float* Cf = (float*)Cout;
#pragma unroll
        for (int u = 0; u < 4; u++) {
            int n = ocol + 16 * u;
            float bias = b0[n];
#pragma unroll
            for (int t = 0; t < 4; t++)
#pragma unroll
                for (int r = 0; r < 4; r++)
                    Cf[(size_t)(orow + 16 * t + r) * N + n] = acc[t][u][r] + bias;
        }
    }
}

// ---------------------------------------------------------------------------
// Pack K and V (bf16 cols of QKV) into fragment-major buffers (unchanged).
// ---------------------------------------------------------------------------
__global__ __launch_bounds__(256)
void kvpack(const ushort* __restrict__ QKV, ushort* __restrict__ Kf,
            ushort* __restrict__ Vf)
{
    __shared__ __align__(16) ushort Kt[64][72];
    __shared__ __align__(16) ushort Vt[64][72];
    const int kt = blockIdx.x, hk = blockIdx.y, b = blockIdx.z;
    const int tid = threadIdx.x;

#pragma unroll
    for (int it = 0; it < 2; it++) {
        int idx = tid + it * 256;
        int r = idx >> 3, c8 = (idx & 7) * 8;
        const ushort* src = QKV + (size_t)(b * SEQ + kt * 64 + r) * NQKV + hk * HDIM + c8;
        *(s16x8*)&Kt[r][c8] = *(const s16x8*)(src + 1024);
        *(s16x8*)&Vt[r][c8] = *(const s16x8*)(src + 1280);
    }
    __syncthreads();

#pragma unroll
    for (int it = 0; it < 2; it++) {
        int idx = tid + it * 256;
        int t32 = idx >> 8, kc = (idx >> 6) & 3, lane = idx & 63;
        int n32 = lane & 31, h5 = lane >> 5;
        s16x8 fr = *(const s16x8*)&Kt[t32 * 32 + n32][kc * 16 + h5 * 8];
        size_t flat = ((size_t)(((b * NKV + hk) * 64 + kt * 2 + t32) * 4 + kc) * 64 + lane) * 8;
        *(s16x8*)(Kf + flat) = fr;
    }
#pragma unroll
    for (int it = 0; it < 2; it++) {
        int idx = tid + it * 256;
        int kcdn = idx >> 6, lane = idx & 63;
        int kc = kcdn >> 1, dn = kcdn & 1;
        int n32 = lane & 31, h5 = lane >> 5;
        s16x8 fr;
#pragma unroll
        for (int j = 0; j < 8; j++)
            fr[j] = (short)Vt[kc * 16 + h5 * 8 + j][dn * 32 + n32];
        size_t flat = ((size_t)(((b * NKV + hk) * 32 + kt) * 8 + kc * 2 + dn) * 64 + lane) * 8;
        *(s16x8*)(Vf + flat) = fr;
    }
}

// ---------------------------------------------------------------------------
// Flash attention v14 = v13 with the P LDS round-trip (8 ds_write_b64 +
// 8 ds_read_b64 per wave-tile) replaced by in-register permlane32_swap.
// Index algebra: QK's S^T gives lane(q=n32,h5) the keys kn*32+(r&3)+8t+4h5;
// PV's A-frag needs lane(q,h5) to hold keys kc*16+h5*8+{0..7}. Quad (t,h5s)
// covers keys 8t+4h5s+{0..3}, so swapping the packed t-even word with the
// t-odd word across lane halves (v_permlane32_swap_b32: a_hi <-> b_lo, lane
// i <-> i+32, same q) leaves BOTH registers per-lane-correct:
//   pa[kn*2+0] = {w0,w1,w2,w3} from (t0w0,t0w1,t1w0,t1w1) after
//   swap(w0,w2), swap(w1,w3); pa[kn*2+1] likewise from t2/t3.
// Per tile: +8 swaps (VALU), -16 DS ops, -Ps buffer (LDS 34816->33280),
// and the PV/QK in-order-DS correctness coupling is GONE (pa WAR only).
// pa[4] is loop-carried: +~16 VGPR (88 -> ~104, still <=128 = 4 waves/SIMD).
// Arithmetic identical to v13 -> absmax must equal 4.882812e-4.
// ---------------------------------------------------------------------------
__global__ __launch_bounds__(512, 2)
void attn_mfma14(const ushort* __restrict__ QKV, const ushort* __restrict__ Kf,
                 const ushort* __restrict__ Vf, ushort* __restrict__ Chi)
{
    __shared__ float OLb[4 * 32 * 64];   // 32,768 B merge buffer
    __shared__ float LLb[4 * 32];        // 512 B

    const int tid = threadIdx.x, w = tid >> 6, lane = tid & 63;
    const int g = w >> 2, ws_ = w & 3;               // q-group, kt-split index
    const int n32 = lane & 31, h5 = lane >> 5;
    const int h = blockIdx.y, b = blockIdx.z, hk = h >> 2;
    const int q0 = blockIdx.x * 64 + g * 32;

    // Q B-fragments (4 k-chunks of 16), hoisted
    const ushort* qrow = QKV + (size_t)(b * SEQ + q0 + n32) * NQKV + h * HDIM + h5 * 8;
    s16x8 aq[4];
#pragma unroll
    for (int kc = 0; kc < 4; kc++) aq[kc] = *(const s16x8*)(qrow + kc * 16);

    f32x16 accO[2];
#pragma unroll
    for (int j = 0; j < 16; j++) { accO[0][j] = 0.f; accO[1][j] = 0.f; }
    float lsum = 0.f;   // per-lane partial l[q=n32] over this lane's key slots

    const ushort* kf0 = Kf + (size_t)(b * NKV + hk) * (64 * 4 * 64 * 8) + (size_t)lane * 8;
    const ushort* vf0 = Vf + (size_t)(b * NKV + hk) * (32 * 8 * 64 * 8) + (size_t)lane * 8;

    s16x8 kreg[8], vreg[8], pa[4];

#define LOAD_K(kt_) do {                                                      \
    _Pragma("unroll")                                                         \
    for (int kn = 0; kn < 2; kn++)                                            \
        _Pragma("unroll")                                                     \
        for (int kc = 0; kc < 4; kc++)                                        \
            kreg[kn * 4 + kc] =                                               \
                *(const s16x8*)(kf0 + (size_t)(((kt_) * 2 + kn) * 4 + kc) * 512); \
} while (0)

#define LOAD_V(kt_) do {                                                      \
    _Pragma("unroll")                                                         \
    for (int kc = 0; kc < 4; kc++)                                            \
        _Pragma("unroll")                                                     \
        for (int dn = 0; dn < 2; dn++)                                        \
            vreg[kc * 2 + dn] =                                               \
                *(const s16x8*)(vf0 + (size_t)((kt_) * 8 + kc * 2 + dn) * 512); \
} while (0)

// S^T = K Q^T -> exp2 (log2e folded into Q) -> lsum f32 tree -> packed bf16
// P fragments built IN REGISTERS via cvtpk + permlane32_swap (no LDS).
#define QK_EXP_PACK() do {                                                    \
    _Pragma("unroll")                                                         \
    for (int kn = 0; kn < 2; kn++) {                                          \
        f32x16 S;                                                             \
        _Pragma("unroll")                                                     \
        for (int j = 0; j < 16; j++) S[j] = 0.f;                              \
        _Pragma("unroll")                                                     \
        for (int kc = 0; kc < 4; kc++)                                        \
            S = __builtin_amdgcn_mfma_f32_32x32x16_bf16(kreg[kn * 4 + kc],    \
                    aq[kc], S, 0, 0, 0);                                      \
        float p[16];                                                          \
        _Pragma("unroll")                                                     \
        for (int reg = 0; reg < 16; reg++) p[reg] = EXP2F(S[reg]);            \
        {                                                                     \
            float a0 = p[0] + p[1],   a1 = p[2] + p[3];                       \
            float a2 = p[4] + p[5],   a3 = p[6] + p[7];                       \
            float a4 = p[8] + p[9],   a5 = p[10] + p[11];                     \
            float a6 = p[12] + p[13], a7 = p[14] + p[15];                     \
            lsum += ((a0 + a1) + (a2 + a3)) + ((a4 + a5) + (a6 + a7));        \
        }                                                                     \
        {                                                                     \
            unsigned w0 = cvtpk2_rhu(p[0],  p[1]);   /* t0 w0 */              \
            unsigned w1 = cvtpk2_rhu(p[2],  p[3]);   /* t0 w1 */              \
            unsigned w2 = cvtpk2_rhu(p[4],  p[5]);   /* t1 w0 */              \
            unsigned w3 = cvtpk2_rhu(p[6],  p[7]);   /* t1 w1 */              \
            plane32_swap(w0, w2); plane32_swap(w1, w3);                       \
            union { s16x8 v; unsigned u[4]; } P0;                             \
            P0.u[0] = w0; P0.u[1] = w1; P0.u[2] = w2; P0.u[3] = w3;           \
            pa[kn * 2 + 0] = P0.v;                                            \
            unsigned w4 = cvtpk2_rhu(p[8],  p[9]);   /* t2 w0 */              \
            unsigned w5 = cvtpk2_rhu(p[10], p[11]);  /* t2 w1 */              \
            unsigned w6 = cvtpk2_rhu(p[12], p[13]);  /* t3 w0 */              \
            unsigned w7 = cvtpk2_rhu(p[14], p[15]);  /* t3 w1 */              \
            plane32_swap(w4, w6); plane32_swap(w5, w7);                       \
            union { s16x8 v; unsigned u[4]; } P1;                             \
            P1.u[0] = w4; P1.u[1] = w5; P1.u[2] = w6; P1.u[3] = w7;           \
            pa[kn * 2 + 1] = P1.v;                                            \
        }                                                                     \
    }                                                                         \
} while (0)

#define PV_STEP() do {                                                        \
    _Pragma("unroll")                                                         \
    for (int kc = 0; kc < 4; kc++) {                                          \
        _Pragma("unroll")                                                     \
        for (int dn = 0; dn < 2; dn++)                                        \
            accO[dn] = __builtin_amdgcn_mfma_f32_32x32x16_bf16(pa[kc],        \
                           vreg[kc * 2 + dn], accO[dn], 0, 0, 0);             \
    }                                                                         \
} while (0)

    // prologue: K0+V0 in flight; QK(t0) waits only K0 (V0 stays outstanding);
    // K1 issued right after QK consumed kreg.
    LOAD_K(ws_);
    LOAD_V(ws_);
    QK_EXP_PACK();
    LOAD_K(ws_ + 4);

#pragma unroll
    for (int i = 1; i < 8; i++) {
        PV_STEP();               // consumes pa(i-1) + vreg(i-1)
        LOAD_V(ws_ + 4 * i);     // V_i: cover = QK(i) below
        QK_EXP_PACK();           // waits K_i (oldest); overwrites pa (WAR ok)
        if (i < 7) LOAD_K(ws_ + 4 * (i + 1));   // K_{i+1}: cover = PV(i)
    }
    // epilogue: last tile's PV
    PV_STEP();

#undef LOAD_K
#undef LOAD_V
#undef QK_EXP_PACK
#undef PV_STEP

    // combine the two h5 halves of l[q=n32] (each lane then holds the full sum)
    lsum += __shfl_xor(lsum, 32, 64);

    const int qq = tid >> 4;          // 0..31
    const int d0 = (tid & 15) * 4;    // 0..60
#pragma unroll
    for (int phase = 0; phase < 2; phase++) {
        if (g == phase) {
#pragma unroll
            for (int reg = 0; reg < 16; reg++) {
                int q = (reg & 3) + 8 * (reg >> 2) + 4 * h5;
                OLb[(ws_ * 32 + q) * 64 + n32]      = accO[0][reg];
                OLb[(ws_ * 32 + q) * 64 + 32 + n32] = accO[1][reg];
            }
            if (h5 == 0) LLb[ws_ * 32 + n32] = lsum;
        }
        __syncthreads();
        {
            float lsum2 = LLb[qq] + LLb[32 + qq] + LLb[64 + qq] + LLb[96 + qq];
            float inv = 1.f / lsum2;
            ushort4 hs;
            float o0 = (OLb[(0 * 32 + qq) * 64 + d0 + 0] + OLb[(1 * 32 + qq) * 64 + d0 + 0] +
                        OLb[(2 * 32 + qq) * 64 + d0 + 0] + OLb[(3 * 32 + qq) * 64 + d0 + 0]) * inv;
            float o1 = (OLb[(0 * 32 + qq) * 64 + d0 + 1] + OLb[(1 * 32 + qq) * 64 + d0 + 1] +
                        OLb[(2 * 32 + qq) * 64 + d0 + 1] + OLb[(3 * 32 + qq) * 64 + d0 + 1]) * inv;
            float o2 = (OLb[(0 * 32 + qq) * 64 + d0 + 2] + OLb[(1 * 32 + qq) * 64 + d0 + 2] +
                        OLb[(2 * 32 + qq) * 64 + d0 + 2] + OLb[(3 * 32 + qq) * 64 + d0 + 2]) * inv;
            float o3 = (OLb[(0 * 32 + qq) * 64 + d0 + 3] + OLb[(1 * 32 + qq) * 64 + d0 + 3] +
                        OLb[(2 * 32 + qq) * 64 + d0 + 3] + OLb[(3 * 32 + qq) * 64 + d0 + 3]) * inv;
            hs.x = f2bf(o0); hs.y = f2bf(o1); hs.z = f2bf(o2); hs.w = f2bf(o3);
            size_t off = (size_t)(b * SEQ + blockIdx.x * 64 + phase * 32 + qq) * HIDDEN
                       + h * HDIM + d0;
            *(ushort4*)(Chi + off) = hs;
        }
        __syncthreads();   // before next phase overwrites merge buffers
    }
}

// ---------------------------------------------------------------------------
extern "C" void kernel_launch(void* const* d_in, const int* in_sizes, int n_in,
                              void* d_out, int out_size, void* d_ws, size_t ws_size,
                              hipStream_t stream)
{
    const float* X  = (const float*)d_in[0];
    const float* Wq = (const float*)d_in[1];
    const float* bq = (const float*)d_in[2];
    const float* Wk = (const float*)d_in[3];
    const float* bk = (const float*)d_in[4];
    const float* Wv = (const float*)d_in[5];
    const float* bv = (const float*)d_in[6];
    const float* Wo = (const float*)d_in[7];
    const float* bo = (const float*)d_in[8];
    float* out = (float*)d_out;

    const int M = BATCH * SEQ;  // 4096
    // ws layout (37 MB): Xb 8 | Ctx 8 | QKVb 12 | Wqkvt 3 | Wot 2 | Kf 2 | Vf 2
    char* ws = (char*)d_ws;
    ushort* Xb    = (ushort*)(ws);
    ushort* Ctx   = (ushort*)(ws + (8u  << 20));
    ushort* QKVb  = (ushort*)(ws + (16u << 20));
    ushort* Wqkvt = (ushort*)(ws + (28u << 20));
    ushort* Wot   = (ushort*)(ws + (31u << 20));
    ushort* Kf    = (ushort*)(ws + (33u << 20));
    ushort* Vf    = (ushort*)(ws + (35u << 20));

    prep<<<dim3(4736), 256, 0, stream>>>(X, Xb, Wq, Wk, Wv, Wqkvt, Wo, Wot);

    gemm_bf<0><<<dim3(NQKV / 128, M / 128), 256, 0, stream>>>(
        Xb, Wqkvt, bq, bk, bv, (void*)QKVb, M, NQKV, HIDDEN);

    kvpack<<<dim3(SEQ / 64, NKV, BATCH), 256, 0, stream>>>(QKVb, Kf, Vf);

    attn_mfma14<<<dim3(SEQ / 64, NHEAD, BATCH), 512, 0, stream>>>(QKVb, Kf, Vf, Ctx);

    gemm_bf<1><<<dim3(HIDDEN / 128, M / 128), 256, 0, stream>>>(
        Ctx, Wot, bo, nullptr, nullptr, (void*)out, M, HIDDEN, HIDDEN);
}

// Round 11
// 191.041 us; speedup vs baseline: 1.0348x; 1.0348x over previous
//
#include <hip/hip_runtime.h>
#include <hip/hip_bf16.h>

#define HIDDEN 1024
#define NHEAD 16
#define NKV 4
#define HDIM 64
#define KVDIM 256
#define SEQ 2048
#define BATCH 2
#define NQKV 1536   // 1024 (Q) + 256 (K) + 256 (V)

typedef __attribute__((ext_vector_type(4)))  float f32x4;
typedef __attribute__((ext_vector_type(16))) float f32x16;
typedef __attribute__((ext_vector_type(8)))  short s16x8;
typedef __attribute__((ext_vector_type(4)))  short s16x4;

#if defined(__has_builtin)
#if __has_builtin(__builtin_amdgcn_exp2f)
#define EXP2F(x) __builtin_amdgcn_exp2f(x)
#else
#define EXP2F(x) exp2f(x)
#endif
#else
#define EXP2F(x) exp2f(x)
#endif

static __device__ __forceinline__ ushort f2bf(float f) {
    union { __hip_bfloat16 b; ushort u; } cv; cv.b = __float2bfloat16(f); return cv.u;
}
// Packed round-half-up f32x2 -> bf16x2 in 3 VALU ops. R8 PROVED raw
// v_cvt_pk_bf16_f32 truncates (biased P -> FAIL); +0x8000 integer-domain
// pre-add restores round-half-up. R9/R10: passes, absmax 4.88e-4 (2.2x margin).
static __device__ __forceinline__ unsigned cvtpk2_rhu(float a, float b) {
    float ah = __uint_as_float(__float_as_uint(a) + 0x8000u);
    float bh = __uint_as_float(__float_as_uint(b) + 0x8000u);
    unsigned r;
    asm("v_cvt_pk_bf16_f32 %0, %1, %2" : "=v"(r) : "v"(ah), "v"(bh));
    return r;
}
// v_permlane32_swap_b32 a, b: exchanges a's high-32 lanes with b's low-32
// lanes (lane i <-> i+32, same q=n32 row). Both results used (T12 pattern).
// R10: -16 DS ops/tile, attn 56.9 -> 54.6 us, VGPR 84.
static __device__ __forceinline__ void plane32_swap(unsigned& a, unsigned& b) {
    asm("v_permlane32_swap_b32 %0, %1" : "+v"(a), "+v"(b));
}
// async global->LDS, 16B per lane. LDS dest = wave-uniform base + lane*16.
static __device__ __forceinline__ void async16(const void* g, void* l) {
    __builtin_amdgcn_global_load_lds((__attribute__((address_space(1))) void*)g,
                                     (__attribute__((address_space(3))) void*)l, 16, 0, 0);
}

// ---------------------------------------------------------------------------
// Fused prep: grid [0,4096) = X fp32->bf16; [4096,4480) = Wq/Wk/Wv transpose;
// [4480,4736) = Wo transpose. One dispatch instead of three.
// ---------------------------------------------------------------------------
__global__ __launch_bounds__(256)
void prep(const float* __restrict__ X, ushort* __restrict__ Xb,
          const float* __restrict__ Wq, const float* __restrict__ Wk,
          const float* __restrict__ Wv, ushort* __restrict__ Tqkv,
          const float* __restrict__ Wo, ushort* __restrict__ Two)
{
    __shared__ float Tl[64][65];
    const int bid = blockIdx.x, tid = threadIdx.x;

    if (bid < 4096) {           // ---- cvt_x: 4096 blocks x 256 thr x float4
        int i = bid * 256 + tid;
        float4 v = ((const float4*)X)[i];
        ushort4 o;
        o.x = f2bf(v.x); o.y = f2bf(v.y); o.z = f2bf(v.z); o.w = f2bf(v.w);
        ((ushort4*)Xb)[i] = o;
        return;
    }

    const float* W; ushort* T; int N, n0, k0, roff;
    if (bid < 4096 + 384) {     // ---- wtrans_qkv (24 x 16)
        int wq = bid - 4096;
        int bx = wq % 24; k0 = (wq / 24) * 64;
        T = Tqkv;
        if (bx < 16)      { W = Wq; N = 1024; n0 = bx * 64;        roff = 0; }
        else if (bx < 20) { W = Wk; N = 256;  n0 = (bx - 16) * 64; roff = 1024; }
        else              { W = Wv; N = 256;  n0 = (bx - 20) * 64; roff = 1280; }
    } else {                    // ---- wtrans_one (Wo, 16 x 16)
        int wo = bid - 4480;
        int bx = wo % 16; k0 = (wo / 16) * 64;
        W = Wo; T = Two; N = 1024; n0 = bx * 64; roff = 0;
    }

#pragma unroll
    for (int it = 0; it < 4; it++) {
        int idx = tid + it * 256;
        int kk = idx >> 4, n4 = (idx & 15) * 4;
        float4 v = *(const float4*)(W + (size_t)(k0 + kk) * N + n0 + n4);
        Tl[kk][n4 + 0] = v.x; Tl[kk][n4 + 1] = v.y;
        Tl[kk][n4 + 2] = v.z; Tl[kk][n4 + 3] = v.w;
    }
    __syncthreads();
#pragma unroll
    for (int it = 0; it < 4; it++) {
        int idx = tid + it * 256;
        int n = idx >> 4, k4 = (idx & 15) * 4;
        ushort4 h4;
        h4.x = f2bf(Tl[k4 + 0][n]); h4.y = f2bf(Tl[k4 + 1][n]);
        h4.z = f2bf(Tl[k4 + 2][n]); h4.w = f2bf(Tl[k4 + 3][n]);
        *(ushort4*)(T + (size_t)(roff + n0 + n) * HIDDEN + k0 + k4) = h4;
    }
}

// ---------------------------------------------------------------------------
// Plain-bf16 MFMA GEMM, fp32 accumulate: C = A[M,K] @ B^T[N,K] + bias.
// R11 changes vs R10 (both arithmetic-identical, FP order preserved):
//  1) BK=64 (32KB LDS): halves the barrier+vmcnt-drain count (the m97
//     structure's ~20% stall) from 32 to 16 pairs at K=1024. kk=0 then kk=1
//     sub-steps == two BK=32 iterations -> bit-identical accumulation.
//  2) Bijective XCD swizzle (T1; nwg%8==0 for both grids: 384, 256):
//     each XCD gets a contiguous work chunk (4 M-rows x all N-tiles), so
//     A-panel re-reads (12x for gemm0) hit its private L2 (~4MB working set)
//     instead of L3.
// 128x128 tile, 4 waves 2x2, 16 MFMA/wave/K-32. Grids: gemm0 (12,32),
// gemm1 (8,32). MODE 0: bf16 out (Q cols scaled 0.125*log2e). MODE 1: fp32.
// ---------------------------------------------------------------------------
template <int MODE>
__global__ __launch_bounds__(256)
void gemm_bf(const ushort* __restrict__ A, const ushort* __restrict__ Bt,
             const float* __restrict__ b0, const float* __restrict__ b1,
             const float* __restrict__ b2, void* __restrict__ Cout,
             int M, int N, int K)
{
    __shared__ __align__(16) ushort Ah[128 * 64];   // 16 KB
    __shared__ __align__(16) ushort Bh[128 * 64];   // 16 KB

    const int tid = threadIdx.x;
    const int lane = tid & 63, wv = tid >> 6;
    const int wr = wv >> 1, wc = wv & 1;
    const int m = lane & 15, c = lane >> 4;

    // XCD-aware swizzle (bijective: nwg % 8 == 0 at both call sites)
    const int nwg = gridDim.x * gridDim.y;
    const int flat = blockIdx.y * gridDim.x + blockIdx.x;
    const int swz = (flat & 7) * (nwg >> 3) + (flat >> 3);
    const int bx = swz % gridDim.x, by = swz / gridDim.x;
    const int row0 = by * 128, col0 = bx * 128;

    // staging: 4 slots/thread each for A and B (128 rows x 64 cols bf16).
    // idx = it*256 + tid: row = idx>>3, col8 = (idx&7)*8. LDS linear (idx*8),
    // wave-uniform base + lane*16 per global_load_lds constraint.
    const ushort* gA[4]; const ushort* gB[4]; int ldsO[4];
#pragma unroll
    for (int it = 0; it < 4; it++) {
        int idx = it * 256 + tid;
        gA[it] = A  + (size_t)(row0 + (idx >> 3)) * K + (idx & 7) * 8;
        gB[it] = Bt + (size_t)(col0 + (idx >> 3)) * K + (idx & 7) * 8;
        ldsO[it] = idx * 8;
    }

    f32x4 acc[4][4];
#pragma unroll
    for (int t = 0; t < 4; t++)
#pragma unroll
        for (int u = 0; u < 4; u++) acc[t][u] = (f32x4){0.f, 0.f, 0.f, 0.f};

    for (int k0 = 0; k0 < K; k0 += 64) {
        __syncthreads();
#pragma unroll
        for (int it = 0; it < 4; it++) {
            async16(gA[it] + k0, Ah + ldsO[it]);
            async16(gB[it] + k0, Bh + ldsO[it]);
        }
        __syncthreads();   // compiler drains vmcnt before s_barrier

#pragma unroll
        for (int kk = 0; kk < 2; kk++) {
            s16x8 ah[4], bh[4];
#pragma unroll
            for (int t = 0; t < 4; t++)
                ah[t] = *(const s16x8*)&Ah[(wr * 64 + t * 16 + m) * 64 + kk * 32 + c * 8];
#pragma unroll
            for (int u = 0; u < 4; u++)
                bh[u] = *(const s16x8*)&Bh[(wc * 64 + u * 16 + m) * 64 + kk * 32 + c * 8];
#pragma unroll
            for (int t = 0; t < 4; t++)
#pragma unroll
                for (int u = 0; u < 4; u++)
                    acc[t][u] = __builtin_amdgcn_mfma_f32_16x16x32_bf16(ah[t], bh[u], acc[t][u], 0, 0, 0);
        }
    }

    const int orow = row0 + wr * 64 + 4 * c;   // + 16t + r
    const int ocol = col0 + wc * 64 + m;       // + 16u
    if (MODE == 0) {
        ushort* Cb = (ushort*)Cout;
#pragma unroll
        for (int u = 0; u < 4; u++) {
            int n = ocol + 16 * u;
            float bias, scl;
            if (n < 1024)      { bias = b0[n];        scl = 0.18033688f; }  // 0.125*log2(e)
            else if (n < 1280) { bias = b1[n - 1024]; scl = 1.0f; }
            else               { bias = b2[n - 1280]; scl = 1.0f; }
#pragma unroll
            for (int t = 0; t < 4; t++)
#pragma unroll
                for (int r = 0; r < 4; r++)
                    Cb[(size_t)(orow + 16 * t + r) * N + n] = f2bf((acc[t][u][r] + bias) * scl);
        }
    } else {
        float* Cf = (float*)Cout;
#pragma unroll
        for (int u = 0; u < 4; u++) {
            int n = ocol + 16 * u;
            float bias = b0[n];
#pragma unroll
            for (int t = 0; t < 4; t++)
#pragma unroll
                for (int r = 0; r < 4; r++)
                    Cf[(size_t)(orow + 16 * t + r) * N + n] = acc[t][u][r] + bias;
        }
    }
}

// ---------------------------------------------------------------------------
// Pack K and V (bf16 cols of QKV) into fragment-major buffers (unchanged).
// ---------------------------------------------------------------------------
__global__ __launch_bounds__(256)
void kvpack(const ushort* __restrict__ QKV, ushort* __restrict__ Kf,
            ushort* __restrict__ Vf)
{
    __shared__ __align__(16) ushort Kt[64][72];
    __shared__ __align__(16) ushort Vt[64][72];
    const int kt = blockIdx.x, hk = blockIdx.y, b = blockIdx.z;
    const int tid = threadIdx.x;

#pragma unroll
    for (int it = 0; it < 2; it++) {
        int idx = tid + it * 256;
        int r = idx >> 3, c8 = (idx & 7) * 8;
        const ushort* src = QKV + (size_t)(b * SEQ + kt * 64 + r) * NQKV + hk * HDIM + c8;
        *(s16x8*)&Kt[r][c8] = *(const s16x8*)(src + 1024);
        *(s16x8*)&Vt[r][c8] = *(const s16x8*)(src + 1280);
    }
    __syncthreads();

#pragma unroll
    for (int it = 0; it < 2; it++) {
        int idx = tid + it * 256;
        int t32 = idx >> 8, kc = (idx >> 6) & 3, lane = idx & 63;
        int n32 = lane & 31, h5 = lane >> 5;
        s16x8 fr = *(const s16x8*)&Kt[t32 * 32 + n32][kc * 16 + h5 * 8];
        size_t flat = ((size_t)(((b * NKV + hk) * 64 + kt * 2 + t32) * 4 + kc) * 64 + lane) * 8;
        *(s16x8*)(Kf + flat) = fr;
    }
#pragma unroll
    for (int it = 0; it < 2; it++) {
        int idx = tid + it * 256;
        int kcdn = idx >> 6, lane = idx & 63;
        int kc = kcdn >> 1, dn = kcdn & 1;
        int n32 = lane & 31, h5 = lane >> 5;
        s16x8 fr;
#pragma unroll
        for (int j = 0; j < 8; j++)
            fr[j] = (short)Vt[kc * 16 + h5 * 8 + j][dn * 32 + n32];
        size_t flat = ((size_t)(((b * NKV + hk) * 32 + kt) * 8 + kc * 2 + dn) * 64 + lane) * 8;
        *(s16x8*)(Vf + flat) = fr;
    }
}

// ---------------------------------------------------------------------------
// Flash attention v14 (FROZEN — measured best: 54.6 us, VGPR 84, LDS 33280):
// S^T QK + in-register P via cvtpk_rhu + permlane32_swap (no P LDS),
// f32-tree lsum, rotated load schedule. absmax 4.882812e-4.
// ---------------------------------------------------------------------------
__global__ __launch_bounds__(512, 2)
void attn_mfma14(const ushort* __restrict__ QKV, const ushort* __restrict__ Kf,
                 const ushort* __restrict__ Vf, ushort* __restrict__ Chi)
{
    __shared__ float OLb[4 * 32 * 64];   // 32,768 B merge buffer
    __shared__ float LLb[4 * 32];        // 512 B

    const int tid = threadIdx.x, w = tid >> 6, lane = tid & 63;
    const int g = w >> 2, ws_ = w & 3;               // q-group, kt-split index
    const int n32 = lane & 31, h5 = lane >> 5;
    const int h = blockIdx.y, b = blockIdx.z, hk = h >> 2;
    const int q0 = blockIdx.x * 64 + g * 32;

    // Q B-fragments (4 k-chunks of 16), hoisted
    const ushort* qrow = QKV + (size_t)(b * SEQ + q0 + n32) * NQKV + h * HDIM + h5 * 8;
    s16x8 aq[4];
#pragma unroll
    for (int kc = 0; kc < 4; kc++) aq[kc] = *(const s16x8*)(qrow + kc * 16);

    f32x16 accO[2];
#pragma unroll
    for (int j = 0; j < 16; j++) { accO[0][j] = 0.f; accO[1][j] = 0.f; }
    float lsum = 0.f;   // per-lane partial l[q=n32] over this lane's key slots

    const ushort* kf0 = Kf + (size_t)(b * NKV + hk) * (64 * 4 * 64 * 8) + (size_t)lane * 8;
    const ushort* vf0 = Vf + (size_t)(b * NKV + hk) * (32 * 8 * 64 * 8) + (size_t)lane * 8;

    s16x8 kreg[8], vreg[8], pa[4];

#define LOAD_K(kt_) do {                                                      \
    _Pragma("unroll")                                                         \
    for (int kn = 0; kn < 2; kn++)                                            \
        _Pragma("unroll")                                                     \
        for (int kc = 0; kc < 4; kc++)                                        \
            kreg[kn * 4 + kc] =                                               \
                *(const s16x8*)(kf0 + (size_t)(((kt_) * 2 + kn) * 4 + kc) * 512); \
} while (0)

#define LOAD_V(kt_) do {                                                      \
    _Pragma("unroll")                                                         \
    for (int kc = 0; kc < 4; kc++)                                            \
        _Pragma("unroll")                                                     \
        for (int dn = 0; dn < 2; dn++)                                        \
            vreg[kc * 2 + dn] =                                               \
                *(const s16x8*)(vf0 + (size_t)((kt_) * 8 + kc * 2 + dn) * 512); \
} while (0)

// S^T = K Q^T -> exp2 (log2e folded into Q) -> lsum f32 tree -> packed bf16
// P fragments built IN REGISTERS via cvtpk + permlane32_swap (no LDS).
#define QK_EXP_PACK() do {                                                    \
    _Pragma("unroll")                                                         \
    for (int kn = 0; kn < 2; kn++) {                                          \
        f32x16 S;                                                             \
        _Pragma("unroll")                                                     \
        for (int j = 0; j < 16; j++) S[j] = 0.f;                              \
        _Pragma("unroll")                                                     \
        for (int kc = 0; kc < 4; kc++)                                        \
            S = __builtin_amdgcn_mfma_f32_32x32x16_bf16(kreg[kn * 4 + kc],    \
                    aq[kc], S, 0, 0, 0);                                      \
        float p[16];                                                          \
        _Pragma("unroll")                                                     \
        for (int reg = 0; reg < 16; reg++) p[reg] = EXP2F(S[reg]);            \
        {                                                                     \
            float a0 = p[0] + p[1],   a1 = p[2] + p[3];                       \
            float a2 = p[4] + p[5],   a3 = p[6] + p[7];                       \
            float a4 = p[8] + p[9],   a5 = p[10] + p[11];                     \
            float a6 = p[12] + p[13], a7 = p[14] + p[15];                     \
            lsum += ((a0 + a1) + (a2 + a3)) + ((a4 + a5) + (a6 + a7));        \
        }                                                                     \
        {                                                                     \
            unsigned w0 = cvtpk2_rhu(p[0],  p[1]);   /* t0 w0 */              \
            unsigned w1 = cvtpk2_rhu(p[2],  p[3]);   /* t0 w1 */              \
            unsigned w2 = cvtpk2_rhu(p[4],  p[5]);   /* t1 w0 */              \
            unsigned w3 = cvtpk2_rhu(p[6],  p[7]);   /* t1 w1 */              \
            plane32_swap(w0, w2); plane32_swap(w1, w3);                       \
            union { s16x8 v; unsigned u[4]; } P0;                             \
            P0.u[0] = w0; P0.u[1] = w1; P0.u[2] = w2; P0.u[3] = w3;           \
            pa[kn * 2 + 0] = P0.v;                                            \
            unsigned w4 = cvtpk2_rhu(p[8],  p[9]);   /* t2 w0 */              \
            unsigned w5 = cvtpk2_rhu(p[10], p[11]);  /* t2 w1 */              \
            unsigned w6 = cvtpk2_rhu(p[12], p[13]);  /* t3 w0 */              \
            unsigned w7 = cvtpk2_rhu(p[14], p[15]);  /* t3 w1 */              \
            plane32_swap(w4, w6); plane32_swap(w5, w7);                       \
            union { s16x8 v; unsigned u[4]; } P1;                             \
            P1.u[0] = w4; P1.u[1] = w5; P1.u[2] = w6; P1.u[3] = w7;           \
            pa[kn * 2 + 1] = P1.v;                                            \
        }                                                                     \
    }                                                                         \
} while (0)

#define PV_STEP() do {                                                        \
    _Pragma("unroll")                                                         \
    for (int kc = 0; kc < 4; kc++) {                                          \
        _Pragma("unroll")                                                     \
        for (int dn = 0; dn < 2; dn++)                                        \
            accO[dn] = __builtin_amdgcn_mfma_f32_32x32x16_bf16(pa[kc],        \
                           vreg[kc * 2 + dn], accO[dn], 0, 0, 0);             \
    }                                                                         \
} while (0)

    // prologue: K0+V0 in flight; QK(t0) waits only K0 (V0 stays outstanding);
    // K1 issued right after QK consumed kreg.
    LOAD_K(ws_);
    LOAD_V(ws_);
    QK_EXP_PACK();
    LOAD_K(ws_ + 4);

#pragma unroll
    for (int i = 1; i < 8; i++) {
        PV_STEP();               // consumes pa(i-1) + vreg(i-1)
        LOAD_V(ws_ + 4 * i);     // V_i: cover = QK(i) below
        QK_EXP_PACK();           // waits K_i (oldest); overwrites pa (WAR ok)
        if (i < 7) LOAD_K(ws_ + 4 * (i + 1));   // K_{i+1}: cover = PV(i)
    }
    // epilogue: last tile's PV
    PV_STEP();

#undef LOAD_K
#undef LOAD_V
#undef QK_EXP_PACK
#undef PV_STEP

    // combine the two h5 halves of l[q=n32] (each lane then holds the full sum)
    lsum += __shfl_xor(lsum, 32, 64);

    const int qq = tid >> 4;          // 0..31
    const int d0 = (tid & 15) * 4;    // 0..60
#pragma unroll
    for (int phase = 0; phase < 2; phase++) {
        if (g == phase) {
#pragma unroll
            for (int reg = 0; reg < 16; reg++) {
                int q = (reg & 3) + 8 * (reg >> 2) + 4 * h5;
                OLb[(ws_ * 32 + q) * 64 + n32]      = accO[0][reg];
                OLb[(ws_ * 32 + q) * 64 + 32 + n32] = accO[1][reg];
            }
            if (h5 == 0) LLb[ws_ * 32 + n32] = lsum;
        }
        __syncthreads();
        {
            float lsum2 = LLb[qq] + LLb[32 + qq] + LLb[64 + qq] + LLb[96 + qq];
            float inv = 1.f / lsum2;
            ushort4 hs;
            float o0 = (OLb[(0 * 32 + qq) * 64 + d0 + 0] + OLb[(1 * 32 + qq) * 64 + d0 + 0] +
                        OLb[(2 * 32 + qq) * 64 + d0 + 0] + OLb[(3 * 32 + qq) * 64 + d0 + 0]) * inv;
            float o1 = (OLb[(0 * 32 + qq) * 64 + d0 + 1] + OLb[(1 * 32 + qq) * 64 + d0 + 1] +
                        OLb[(2 * 32 + qq) * 64 + d0 + 1] + OLb[(3 * 32 + qq) * 64 + d0 + 1]) * inv;
            float o2 = (OLb[(0 * 32 + qq) * 64 + d0 + 2] + OLb[(1 * 32 + qq) * 64 + d0 + 2] +
                        OLb[(2 * 32 + qq) * 64 + d0 + 2] + OLb[(3 * 32 + qq) * 64 + d0 + 2]) * inv;
            float o3 = (OLb[(0 * 32 + qq) * 64 + d0 + 3] + OLb[(1 * 32 + qq) * 64 + d0 + 3] +
                        OLb[(2 * 32 + qq) * 64 + d0 + 3] + OLb[(3 * 32 + qq) * 64 + d0 + 3]) * inv;
            hs.x = f2bf(o0); hs.y = f2bf(o1); hs.z = f2bf(o2); hs.w = f2bf(o3);
            size_t off = (size_t)(b * SEQ + blockIdx.x * 64 + phase * 32 + qq) * HIDDEN
                       + h * HDIM + d0;
            *(ushort4*)(Chi + off) = hs;
        }
        __syncthreads();   // before next phase overwrites merge buffers
    }
}

// ---------------------------------------------------------------------------
extern "C" void kernel_launch(void* const* d_in, const int* in_sizes, int n_in,
                              void* d_out, int out_size, void* d_ws, size_t ws_size,
                              hipStream_t stream)
{
    const float* X  = (const float*)d_in[0];
    const float* Wq = (const float*)d_in[1];
    const float* bq = (const float*)d_in[2];
    const float* Wk = (const float*)d_in[3];
    const float* bk = (const float*)d_in[4];
    const float* Wv = (const float*)d_in[5];
    const float* bv = (const float*)d_in[6];
    const float* Wo = (const float*)d_in[7];
    const float* bo = (const float*)d_in[8];
    float* out = (float*)d_out;

    const int M = BATCH * SEQ;  // 4096
    // ws layout (37 MB): Xb 8 | Ctx 8 | QKVb 12 | Wqkvt 3 | Wot 2 | Kf 2 | Vf 2
    char* ws = (char*)d_ws;
    ushort* Xb    = (ushort*)(ws);
    ushort* Ctx   = (ushort*)(ws + (8u  << 20));
    ushort* QKVb  = (ushort*)(ws + (16u << 20));
    ushort* Wqkvt = (ushort*)(ws + (28u << 20));
    ushort* Wot   = (ushort*)(ws + (31u << 20));
    ushort* Kf    = (ushort*)(ws + (33u << 20));
    ushort* Vf    = (ushort*)(ws + (35u << 20));

    prep<<<dim3(4736), 256, 0, stream>>>(X, Xb, Wq, Wk, Wv, Wqkvt, Wo, Wot);

    gemm_bf<0><<<dim3(NQKV / 128, M / 128), 256, 0, stream>>>(
        Xb, Wqkvt, bq, bk, bv, (void*)QKVb, M, NQKV, HIDDEN);

    kvpack<<<dim3(SEQ / 64, NKV, BATCH), 256, 0, stream>>>(QKVb, Kf, Vf);

    attn_mfma14<<<dim3(SEQ / 64, NHEAD, BATCH), 512, 0, stream>>>(QKVb, Kf, Vf, Ctx);

    gemm_bf<1><<<dim3(HIDDEN / 128, M / 128), 256, 0, stream>>>(
        Ctx, Wot, bo, nullptr, nullptr, (void*)out, M, HIDDEN, HIDDEN);
}

// Round 12
// 186.612 us; speedup vs baseline: 1.0594x; 1.0237x over previous
//
#include <hip/hip_runtime.h>
#include <hip/hip_bf16.h>

#define HIDDEN 1024
#define NHEAD 16
#define NKV 4
#define HDIM 64
#define KVDIM 256
#define SEQ 2048
#define BATCH 2
#define NQKV 1536   // 1024 (Q) + 256 (K) + 256 (V)

typedef __attribute__((ext_vector_type(4)))  float f32x4;
typedef __attribute__((ext_vector_type(16))) float f32x16;
typedef __attribute__((ext_vector_type(8)))  short s16x8;
typedef __attribute__((ext_vector_type(4)))  short s16x4;

#if defined(__has_builtin)
#if __has_builtin(__builtin_amdgcn_exp2f)
#define EXP2F(x) __builtin_amdgcn_exp2f(x)
#else
#define EXP2F(x) exp2f(x)
#endif
#else
#define EXP2F(x) exp2f(x)
#endif

static __device__ __forceinline__ ushort f2bf(float f) {
    union { __hip_bfloat16 b; ushort u; } cv; cv.b = __float2bfloat16(f); return cv.u;
}
// Packed round-half-up f32x2 -> bf16x2 in 3 VALU ops. R8 PROVED raw
// v_cvt_pk_bf16_f32 truncates (biased P -> FAIL); +0x8000 integer-domain
// pre-add restores round-half-up. R9-R11: passes, absmax 4.88e-4.
static __device__ __forceinline__ unsigned cvtpk2_rhu(float a, float b) {
    float ah = __uint_as_float(__float_as_uint(a) + 0x8000u);
    float bh = __uint_as_float(__float_as_uint(b) + 0x8000u);
    unsigned r;
    asm("v_cvt_pk_bf16_f32 %0, %1, %2" : "=v"(r) : "v"(ah), "v"(bh));
    return r;
}
// v_permlane32_swap_b32: a_hi <-> b_lo (lane i <-> i+32, same q=n32 row).
// R10: -16 DS ops/tile, attn 56.9 -> 54.6 us, VGPR 84.
static __device__ __forceinline__ void plane32_swap(unsigned& a, unsigned& b) {
    asm("v_permlane32_swap_b32 %0, %1" : "+v"(a), "+v"(b));
}
// async global->LDS, 16B per lane. LDS dest = wave-uniform base + lane*16.
static __device__ __forceinline__ void async16(const void* g, void* l) {
    __builtin_amdgcn_global_load_lds((__attribute__((address_space(1))) void*)g,
                                     (__attribute__((address_space(3))) void*)l, 16, 0, 0);
}

// ---------------------------------------------------------------------------
// Fused prep: grid [0,4096) = X fp32->bf16; [4096,4480) = Wq/Wk/Wv transpose;
// [4480,4736) = Wo transpose. One dispatch instead of three.
// ---------------------------------------------------------------------------
__global__ __launch_bounds__(256)
void prep(const float* __restrict__ X, ushort* __restrict__ Xb,
          const float* __restrict__ Wq, const float* __restrict__ Wk,
          const float* __restrict__ Wv, ushort* __restrict__ Tqkv,
          const float* __restrict__ Wo, ushort* __restrict__ Two)
{
    __shared__ float Tl[64][65];
    const int bid = blockIdx.x, tid = threadIdx.x;

    if (bid < 4096) {           // ---- cvt_x: 4096 blocks x 256 thr x float4
        int i = bid * 256 + tid;
        float4 v = ((const float4*)X)[i];
        ushort4 o;
        o.x = f2bf(v.x); o.y = f2bf(v.y); o.z = f2bf(v.z); o.w = f2bf(v.w);
        ((ushort4*)Xb)[i] = o;
        return;
    }

    const float* W; ushort* T; int N, n0, k0, roff;
    if (bid < 4096 + 384) {     // ---- wtrans_qkv (24 x 16)
        int wq = bid - 4096;
        int bx = wq % 24; k0 = (wq / 24) * 64;
        T = Tqkv;
        if (bx < 16)      { W = Wq; N = 1024; n0 = bx * 64;        roff = 0; }
        else if (bx < 20) { W = Wk; N = 256;  n0 = (bx - 16) * 64; roff = 1024; }
        else              { W = Wv; N = 256;  n0 = (bx - 20) * 64; roff = 1280; }
    } else {                    // ---- wtrans_one (Wo, 16 x 16)
        int wo = bid - 4480;
        int bx = wo % 16; k0 = (wo / 16) * 64;
        W = Wo; T = Two; N = 1024; n0 = bx * 64; roff = 0;
    }

#pragma unroll
    for (int it = 0; it < 4; it++) {
        int idx = tid + it * 256;
        int kk = idx >> 4, n4 = (idx & 15) * 4;
        float4 v = *(const float4*)(W + (size_t)(k0 + kk) * N + n0 + n4);
        Tl[kk][n4 + 0] = v.x; Tl[kk][n4 + 1] = v.y;
        Tl[kk][n4 + 2] = v.z; Tl[kk][n4 + 3] = v.w;
    }
    __syncthreads();
#pragma unroll
    for (int it = 0; it < 4; it++) {
        int idx = tid + it * 256;
        int n = idx >> 4, k4 = (idx & 15) * 4;
        ushort4 h4;
        h4.x = f2bf(Tl[k4 + 0][n]); h4.y = f2bf(Tl[k4 + 1][n]);
        h4.z = f2bf(Tl[k4 + 2][n]); h4.w = f2bf(Tl[k4 + 3][n]);
        *(ushort4*)(T + (size_t)(roff + n0 + n) * HIDDEN + k0 + k4) = h4;
    }
}

// ---------------------------------------------------------------------------
// Plain-bf16 MFMA GEMM, fp32 accumulate: C = A[M,K] @ B^T[N,K] + bias.
// 128x128 tile, BK=64 (32KB staging), 4 waves 2x2, bijective XCD swizzle
// (R11: non-attn 143 -> ~101 us normalized — keep).
// R12: kvpack FUSED into the K/V-column blocks' epilogue (MODE 0, bx>=8):
// those blocks skip the QKVb write, stage their bf16 tile in LDS (reusing
// the 32KB Ah/Bh allocation after a barrier; 34.8KB total), and emit the
// kvpack gather verbatim to Kf/Vf (K: row-contiguous b128 reads; V: column
// gathers; stores coalesce to 1KB/group). Data bits identical to the
// unfused path (same acc+bias -> f2bf), so absmax must stay 4.882812e-4.
// MODE 0: Q cols -> bf16 QKVb (scaled 0.125*log2e); K/V cols -> Kf/Vf.
// MODE 1: fp32 out.
// ---------------------------------------------------------------------------
template <int MODE>
__global__ __launch_bounds__(256)
void gemm_bf(const ushort* __restrict__ A, const ushort* __restrict__ Bt,
             const float* __restrict__ b0, const float* __restrict__ b1,
             const float* __restrict__ b2, void* __restrict__ Cout,
             ushort* __restrict__ Kf, ushort* __restrict__ Vf,
             int M, int N, int K)
{
    // smem: K-loop uses [0,16384) as Ah(8192 ushorts)+Bh(8192); K/V epilogue
    // reuses all 17408 ushorts as a [128][136] bf16 tile (34,816 B).
    __shared__ __align__(16) ushort smem[17408];
    ushort* Ah = smem;
    ushort* Bh = smem + 128 * 64;

    const int tid = threadIdx.x;
    const int lane = tid & 63, wv = tid >> 6;
    const int wr = wv >> 1, wc = wv & 1;
    const int m = lane & 15, c = lane >> 4;

    // XCD-aware swizzle (bijective: nwg % 8 == 0 at both call sites)
    const int nwg = gridDim.x * gridDim.y;
    const int flat = blockIdx.y * gridDim.x + blockIdx.x;
    const int swz = (flat & 7) * (nwg >> 3) + (flat >> 3);
    const int bx = swz % gridDim.x, by = swz / gridDim.x;
    const int row0 = by * 128, col0 = bx * 128;

    const ushort* gA[4]; const ushort* gB[4]; int ldsO[4];
#pragma unroll
    for (int it = 0; it < 4; it++) {
        int idx = it * 256 + tid;
        gA[it] = A  + (size_t)(row0 + (idx >> 3)) * K + (idx & 7) * 8;
        gB[it] = Bt + (size_t)(col0 + (idx >> 3)) * K + (idx & 7) * 8;
        ldsO[it] = idx * 8;
    }

    f32x4 acc[4][4];
#pragma unroll
    for (int t = 0; t < 4; t++)
#pragma unroll
        for (int u = 0; u < 4; u++) acc[t][u] = (f32x4){0.f, 0.f, 0.f, 0.f};

    for (int k0 = 0; k0 < K; k0 += 64) {
        __syncthreads();
#pragma unroll
        for (int it = 0; it < 4; it++) {
            async16(gA[it] + k0, Ah + ldsO[it]);
            async16(gB[it] + k0, Bh + ldsO[it]);
        }
        __syncthreads();   // compiler drains vmcnt before s_barrier

#pragma unroll
        for (int kk = 0; kk < 2; kk++) {
            s16x8 ah[4], bh[4];
#pragma unroll
            for (int t = 0; t < 4; t++)
                ah[t] = *(const s16x8*)&Ah[(wr * 64 + t * 16 + m) * 64 + kk * 32 + c * 8];
#pragma unroll
            for (int u = 0; u < 4; u++)
                bh[u] = *(const s16x8*)&Bh[(wc * 64 + u * 16 + m) * 64 + kk * 32 + c * 8];
#pragma unroll
            for (int t = 0; t < 4; t++)
#pragma unroll
                for (int u = 0; u < 4; u++)
                    acc[t][u] = __builtin_amdgcn_mfma_f32_16x16x32_bf16(ah[t], bh[u], acc[t][u], 0, 0, 0);
        }
    }

    const int orow = row0 + wr * 64 + 4 * c;   // + 16t + r
    const int ocol = col0 + wc * 64 + m;       // + 16u

    if (MODE == 0 && bx >= 8) {
        // ---- fused kvpack: K blocks bx in {8,9}, V blocks in {10,11} ----
        __syncthreads();   // all waves done reading Ah/Bh
        // stage bf16 tile [128][136] (row = block-local seq row, col = 2 heads)
#pragma unroll
        for (int u = 0; u < 4; u++) {
            int nloc = wc * 64 + m + 16 * u;
            int gn = col0 + nloc;
            float bias = (bx < 10) ? b1[gn - 1024] : b2[gn - 1280];
#pragma unroll
            for (int t = 0; t < 4; t++)
#pragma unroll
                for (int r = 0; r < 4; r++)
                    smem[(wr * 64 + 4 * c + 16 * t + r) * 136 + nloc] =
                        f2bf(acc[t][u][r] + bias);
        }
        __syncthreads();

        const int b_  = row0 >> 11;           // batch
        const int kt0 = (row0 & 2047) >> 6;   // first of 2 kt tiles
        const int hk_base = (bx & 1) * 2;     // 8,10 -> hk 0,1; 9,11 -> hk 2,3

        if (bx < 10) {   // K gather (kvpack layout, lifted verbatim)
#pragma unroll
            for (int it = 0; it < 8; it++) {
                int idx = it * 256 + tid;
                int lane_ = idx & 63, grp = idx >> 6;
                int kc = grp & 3, t32 = (grp >> 2) & 1;
                int ktt = (grp >> 3) & 1, hh = (grp >> 4) & 1;
                int n32_ = lane_ & 31, h5_ = lane_ >> 5;
                s16x8 fr = *(const s16x8*)&smem[(ktt * 64 + t32 * 32 + n32_) * 136
                                                + hh * 64 + kc * 16 + h5_ * 8];
                int hk = hk_base + hh, kt = kt0 + ktt;
                size_t flatK = ((size_t)(((b_ * NKV + hk) * 64 + kt * 2 + t32) * 4 + kc) * 64
                                + lane_) * 8;
                *(s16x8*)(Kf + flatK) = fr;
            }
        } else {         // V gather (column reads, kvpack layout)
#pragma unroll
            for (int it = 0; it < 8; it++) {
                int idx = it * 256 + tid;
                int lane_ = idx & 63, grp = idx >> 6;
                int dn = grp & 1, kc = (grp >> 1) & 3;
                int ktt = (grp >> 3) & 1, hh = (grp >> 4) & 1;
                int n32_ = lane_ & 31, h5_ = lane_ >> 5;
                s16x8 fr;
#pragma unroll
                for (int j = 0; j < 8; j++)
                    fr[j] = (short)smem[(ktt * 64 + kc * 16 + h5_ * 8 + j) * 136
                                        + hh * 64 + dn * 32 + n32_];
                int hk = hk_base + hh, kt = kt0 + ktt;
                size_t flatV = ((size_t)(((b_ * NKV + hk) * 32 + kt) * 8 + kc * 2 + dn) * 64
                                + lane_) * 8;
                *(s16x8*)(Vf + flatV) = fr;
            }
        }
        return;
    }

    if (MODE == 0) {
        // Q columns only (bx < 8): bf16 out, scaled 0.125*log2(e)
        ushort* Cb = (ushort*)Cout;
#pragma unroll
        for (int u = 0; u < 4; u++) {
            int n = ocol + 16 * u;
            float bias = b0[n];
#pragma unroll
            for (int t = 0; t < 4; t++)
#pragma unroll
                for (int r = 0; r < 4; r++)
                    Cb[(size_t)(orow + 16 * t + r) * N + n] =
                        f2bf((acc[t][u][r] + bias) * 0.18033688f);
        }
    } else {
        float* Cf = (float*)Cout;
#pragma unroll
        for (int u = 0; u < 4; u++) {
            int n = ocol + 16 * u;
            float bias = b0[n];
#pragma unroll
            for (int t = 0; t < 4; t++)
#pragma unroll
                for (int r = 0; r < 4; r++)
                    Cf[(size_t)(orow + 16 * t + r) * N + n] = acc[t][u][r] + bias;
        }
    }
}

// ---------------------------------------------------------------------------
// Flash attention v14 (FROZEN — measured best: 54.6 us fast-container, VGPR
// 84, LDS 33280): S^T QK + in-register P via cvtpk_rhu + permlane32_swap,
// f32-tree lsum, rotated load schedule. absmax 4.882812e-4.
// ---------------------------------------------------------------------------
__global__ __launch_bounds__(512, 2)
void attn_mfma14(const ushort* __restrict__ QKV, const ushort* __restrict__ Kf,
                 const ushort* __restrict__ Vf, ushort* __restrict__ Chi)
{
    __shared__ float OLb[4 * 32 * 64];   // 32,768 B merge buffer
    __shared__ float LLb[4 * 32];        // 512 B

    const int tid = threadIdx.x, w = tid >> 6, lane = tid & 63;
    const int g = w >> 2, ws_ = w & 3;               // q-group, kt-split index
    const int n32 = lane & 31, h5 = lane >> 5;
    const int h = blockIdx.y, b = blockIdx.z, hk = h >> 2;
    const int q0 = blockIdx.x * 64 + g * 32;

    // Q B-fragments (4 k-chunks of 16), hoisted
    const ushort* qrow = QKV + (size_t)(b * SEQ + q0 + n32) * NQKV + h * HDIM + h5 * 8;
    s16x8 aq[4];
#pragma unroll
    for (int kc = 0; kc < 4; kc++) aq[kc] = *(const s16x8*)(qrow + kc * 16);

    f32x16 accO[2];
#pragma unroll
    for (int j = 0; j < 16; j++) { accO[0][j] = 0.f; accO[1][j] = 0.f; }
    float lsum = 0.f;   // per-lane partial l[q=n32] over this lane's key slots

    const ushort* kf0 = Kf + (size_t)(b * NKV + hk) * (64 * 4 * 64 * 8) + (size_t)lane * 8;
    const ushort* vf0 = Vf + (size_t)(b * NKV + hk) * (32 * 8 * 64 * 8) + (size_t)lane * 8;

    s16x8 kreg[8], vreg[8], pa[4];

#define LOAD_K(kt_) do {                                                      \
    _Pragma("unroll")                                                         \
    for (int kn = 0; kn < 2; kn++)                                            \
        _Pragma("unroll")                                                     \
        for (int kc = 0; kc < 4; kc++)                                        \
            kreg[kn * 4 + kc] =                                               \
                *(const s16x8*)(kf0 + (size_t)(((kt_) * 2 + kn) * 4 + kc) * 512); \
} while (0)

#define LOAD_V(kt_) do {                                                      \
    _Pragma("unroll")                                                         \
    for (int kc = 0; kc < 4; kc++)                                            \
        _Pragma("unroll")                                                     \
        for (int dn = 0; dn < 2; dn++)                                        \
            vreg[kc * 2 + dn] =                                               \
                *(const s16x8*)(vf0 + (size_t)((kt_) * 8 + kc * 2 + dn) * 512); \
} while (0)

// S^T = K Q^T -> exp2 (log2e folded into Q) -> lsum f32 tree -> packed bf16
// P fragments built IN REGISTERS via cvtpk + permlane32_swap (no LDS).
#define QK_EXP_PACK() do {                                                    \
    _Pragma("unroll")                                                         \
    for (int kn = 0; kn < 2; kn++) {                                          \
        f32x16 S;                                                             \
        _Pragma("unroll")                                                     \
        for (int j = 0; j < 16; j++) S[j] = 0.f;                              \
        _Pragma("unroll")                                                     \
        for (int kc = 0; kc < 4; kc++)                                        \
            S = __builtin_amdgcn_mfma_f32_32x32x16_bf16(kreg[kn * 4 + kc],    \
                    aq[kc], S, 0, 0, 0);                                      \
        float p[16];                                                          \
        _Pragma("unroll")                                                     \
        for (int reg = 0; reg < 16; reg++) p[reg] = EXP2F(S[reg]);            \
        {                                                                     \
            float a0 = p[0] + p[1],   a1 = p[2] + p[3];                       \
            float a2 = p[4] + p[5],   a3 = p[6] + p[7];                       \
            float a4 = p[8] + p[9],   a5 = p[10] + p[11];                     \
            float a6 = p[12] + p[13], a7 = p[14] + p[15];                     \
            lsum += ((a0 + a1) + (a2 + a3)) + ((a4 + a5) + (a6 + a7));        \
        }                                                                     \
        {                                                                     \
            unsigned w0 = cvtpk2_rhu(p[0],  p[1]);   /* t0 w0 */              \
            unsigned w1 = cvtpk2_rhu(p[2],  p[3]);   /* t0 w1 */              \
            unsigned w2 = cvtpk2_rhu(p[4],  p[5]);   /* t1 w0 */              \
            unsigned w3 = cvtpk2_rhu(p[6],  p[7]);   /* t1 w1 */              \
            plane32_swap(w0, w2); plane32_swap(w1, w3);                       \
            union { s16x8 v; unsigned u[4]; } P0;                             \
            P0.u[0] = w0; P0.u[1] = w1; P0.u[2] = w2; P0.u[3] = w3;           \
            pa[kn * 2 + 0] = P0.v;                                            \
            unsigned w4 = cvtpk2_rhu(p[8],  p[9]);   /* t2 w0 */              \
            unsigned w5 = cvtpk2_rhu(p[10], p[11]);  /* t2 w1 */              \
            unsigned w6 = cvtpk2_rhu(p[12], p[13]);  /* t3 w0 */              \
            unsigned w7 = cvtpk2_rhu(p[14], p[15]);  /* t3 w1 */              \
            plane32_swap(w4, w6); plane32_swap(w5, w7);                       \
            union { s16x8 v; unsigned u[4]; } P1;                             \
            P1.u[0] = w4; P1.u[1] = w5; P1.u[2] = w6; P1.u[3] = w7;           \
            pa[kn * 2 + 1] = P1.v;                                            \
        }                                                                     \
    }                                                                         \
} while (0)

#define PV_STEP() do {                                                        \
    _Pragma("unroll")                                                         \
    for (int kc = 0; kc < 4; kc++) {                                          \
        _Pragma("unroll")                                                     \
        for (int dn = 0; dn < 2; dn++)                                        \
            accO[dn] = __builtin_amdgcn_mfma_f32_32x32x16_bf16(pa[kc],        \
                           vreg[kc * 2 + dn], accO[dn], 0, 0, 0);             \
    }                                                                         \
} while (0)

    // prologue: K0+V0 in flight; QK(t0) waits only K0 (V0 stays outstanding);
    // K1 issued right after QK consumed kreg.
    LOAD_K(ws_);
    LOAD_V(ws_);
    QK_EXP_PACK();
    LOAD_K(ws_ + 4);

#pragma unroll
    for (int i = 1; i < 8; i++) {
        PV_STEP();               // consumes pa(i-1) + vreg(i-1)
        LOAD_V(ws_ + 4 * i);     // V_i: cover = QK(i) below
        QK_EXP_PACK();           // waits K_i (oldest); overwrites pa (WAR ok)
        if (i < 7) LOAD_K(ws_ + 4 * (i + 1));   // K_{i+1}: cover = PV(i)
    }
    // epilogue: last tile's PV
    PV_STEP();

#undef LOAD_K
#undef LOAD_V
#undef QK_EXP_PACK
#undef PV_STEP

    // combine the two h5 halves of l[q=n32] (each lane then holds the full sum)
    lsum += __shfl_xor(lsum, 32, 64);

    const int qq = tid >> 4;          // 0..31
    const int d0 = (tid & 15) * 4;    // 0..60
#pragma unroll
    for (int phase = 0; phase < 2; phase++) {
        if (g == phase) {
#pragma unroll
            for (int reg = 0; reg < 16; reg++) {
                int q = (reg & 3) + 8 * (reg >> 2) + 4 * h5;
                OLb[(ws_ * 32 + q) * 64 + n32]      = accO[0][reg];
                OLb[(ws_ * 32 + q) * 64 + 32 + n32] = accO[1][reg];
            }
            if (h5 == 0) LLb[ws_ * 32 + n32] = lsum;
        }
        __syncthreads();
        {
            float lsum2 = LLb[qq] + LLb[32 + qq] + LLb[64 + qq] + LLb[96 + qq];
            float inv = 1.f / lsum2;
            ushort4 hs;
            float o0 = (OLb[(0 * 32 + qq) * 64 + d0 + 0] + OLb[(1 * 32 + qq) * 64 + d0 + 0] +
                        OLb[(2 * 32 + qq) * 64 + d0 + 0] + OLb[(3 * 32 + qq) * 64 + d0 + 0]) * inv;
            float o1 = (OLb[(0 * 32 + qq) * 64 + d0 + 1] + OLb[(1 * 32 + qq) * 64 + d0 + 1] +
                        OLb[(2 * 32 + qq) * 64 + d0 + 1] + OLb[(3 * 32 + qq) * 64 + d0 + 1]) * inv;
            float o2 = (OLb[(0 * 32 + qq) * 64 + d0 + 2] + OLb[(1 * 32 + qq) * 64 + d0 + 2] +
                        OLb[(2 * 32 + qq) * 64 + d0 + 2] + OLb[(3 * 32 + qq) * 64 + d0 + 2]) * inv;
            float o3 = (OLb[(0 * 32 + qq) * 64 + d0 + 3] + OLb[(1 * 32 + qq) * 64 + d0 + 3] +
                        OLb[(2 * 32 + qq) * 64 + d0 + 3] + OLb[(3 * 32 + qq) * 64 + d0 + 3]) * inv;
            hs.x = f2bf(o0); hs.y = f2bf(o1); hs.z = f2bf(o2); hs.w = f2bf(o3);
            size_t off = (size_t)(b * SEQ + blockIdx.x * 64 + phase * 32 + qq) * HIDDEN
                       + h * HDIM + d0;
            *(ushort4*)(Chi + off) = hs;
        }
        __syncthreads();   // before next phase overwrites merge buffers
    }
}

// ---------------------------------------------------------------------------
extern "C" void kernel_launch(void* const* d_in, const int* in_sizes, int n_in,
                              void* d_out, int out_size, void* d_ws, size_t ws_size,
                              hipStream_t stream)
{
    const float* X  = (const float*)d_in[0];
    const float* Wq = (const float*)d_in[1];
    const float* bq = (const float*)d_in[2];
    const float* Wk = (const float*)d_in[3];
    const float* bk = (const float*)d_in[4];
    const float* Wv = (const float*)d_in[5];
    const float* bv = (const float*)d_in[6];
    const float* Wo = (const float*)d_in[7];
    const float* bo = (const float*)d_in[8];
    float* out = (float*)d_out;

    const int M = BATCH * SEQ;  // 4096
    // ws layout (37 MB): Xb 8 | Ctx 8 | QKVb 12 | Wqkvt 3 | Wot 2 | Kf 2 | Vf 2
    char* ws = (char*)d_ws;
    ushort* Xb    = (ushort*)(ws);
    ushort* Ctx   = (ushort*)(ws + (8u  << 20));
    ushort* QKVb  = (ushort*)(ws + (16u << 20));
    ushort* Wqkvt = (ushort*)(ws + (28u << 20));
    ushort* Wot   = (ushort*)(ws + (31u << 20));
    ushort* Kf    = (ushort*)(ws + (33u << 20));
    ushort* Vf    = (ushort*)(ws + (35u << 20));

    prep<<<dim3(4736), 256, 0, stream>>>(X, Xb, Wq, Wk, Wv, Wqkvt, Wo, Wot);

    // gemm0 now also produces Kf/Vf directly (kvpack fused into bx>=8 blocks)
    gemm_bf<0><<<dim3(NQKV / 128, M / 128), 256, 0, stream>>>(
        Xb, Wqkvt, bq, bk, bv, (void*)QKVb, Kf, Vf, M, NQKV, HIDDEN);

    attn_mfma14<<<dim3(SEQ / 64, NHEAD, BATCH), 512, 0, stream>>>(QKVb, Kf, Vf, Ctx);

    gemm_bf<1><<<dim3(HIDDEN / 128, M / 128), 256, 0, stream>>>(
        Ctx, Wot, bo, nullptr, nullptr, (void*)out, nullptr, nullptr,
        M, HIDDEN, HIDDEN);
}

// Round 13
// 184.285 us; speedup vs baseline: 1.0727x; 1.0126x over previous
//
#include <hip/hip_runtime.h>
#include <hip/hip_bf16.h>

#define HIDDEN 1024
#define NHEAD 16
#define NKV 4
#define HDIM 64
#define KVDIM 256
#define SEQ 2048
#define BATCH 2
#define NQKV 1536   // 1024 (Q) + 256 (K) + 256 (V)

typedef __attribute__((ext_vector_type(4)))  float f32x4;
typedef __attribute__((ext_vector_type(16))) float f32x16;
typedef __attribute__((ext_vector_type(8)))  short s16x8;
typedef __attribute__((ext_vector_type(4)))  short s16x4;

#if defined(__has_builtin)
#if __has_builtin(__builtin_amdgcn_exp2f)
#define EXP2F(x) __builtin_amdgcn_exp2f(x)
#else
#define EXP2F(x) exp2f(x)
#endif
#else
#define EXP2F(x) exp2f(x)
#endif

static __device__ __forceinline__ ushort f2bf(float f) {
    union { __hip_bfloat16 b; ushort u; } cv; cv.b = __float2bfloat16(f); return cv.u;
}
// Packed round-half-up f32x2 -> bf16x2 in 3 VALU ops. R8 PROVED raw
// v_cvt_pk_bf16_f32 truncates (biased P -> FAIL); +0x8000 integer-domain
// pre-add restores round-half-up. R9-R12: passes, absmax 4.88e-4.
static __device__ __forceinline__ unsigned cvtpk2_rhu(float a, float b) {
    float ah = __uint_as_float(__float_as_uint(a) + 0x8000u);
    float bh = __uint_as_float(__float_as_uint(b) + 0x8000u);
    unsigned r;
    asm("v_cvt_pk_bf16_f32 %0, %1, %2" : "=v"(r) : "v"(ah), "v"(bh));
    return r;
}
// v_permlane32_swap_b32: a_hi <-> b_lo (lane i <-> i+32, same q=n32 row).
// R10: -16 DS ops/tile, attn 56.9 -> 54.6 us, VGPR 84.
static __device__ __forceinline__ void plane32_swap(unsigned& a, unsigned& b) {
    asm("v_permlane32_swap_b32 %0, %1" : "+v"(a), "+v"(b));
}
// async global->LDS, 16B per lane. LDS dest = wave-uniform base + lane*16.
static __device__ __forceinline__ void async16(const void* g, void* l) {
    __builtin_amdgcn_global_load_lds((__attribute__((address_space(1))) void*)g,
                                     (__attribute__((address_space(3))) void*)l, 16, 0, 0);
}

// ---------------------------------------------------------------------------
// Fused prep: grid [0,4096) = X fp32->bf16; [4096,4480) = Wq/Wk/Wv transpose;
// [4480,4736) = Wo transpose. One dispatch instead of three.
// ---------------------------------------------------------------------------
__global__ __launch_bounds__(256)
void prep(const float* __restrict__ X, ushort* __restrict__ Xb,
          const float* __restrict__ Wq, const float* __restrict__ Wk,
          const float* __restrict__ Wv, ushort* __restrict__ Tqkv,
          const float* __restrict__ Wo, ushort* __restrict__ Two)
{
    __shared__ float Tl[64][65];
    const int bid = blockIdx.x, tid = threadIdx.x;

    if (bid < 4096) {           // ---- cvt_x: 4096 blocks x 256 thr x float4
        int i = bid * 256 + tid;
        float4 v = ((const float4*)X)[i];
        ushort4 o;
        o.x = f2bf(v.x); o.y = f2bf(v.y); o.z = f2bf(v.z); o.w = f2bf(v.w);
        ((ushort4*)Xb)[i] = o;
        return;
    }

    const float* W; ushort* T; int N, n0, k0, roff;
    if (bid < 4096 + 384) {     // ---- wtrans_qkv (24 x 16)
        int wq = bid - 4096;
        int bx = wq % 24; k0 = (wq / 24) * 64;
        T = Tqkv;
        if (bx < 16)      { W = Wq; N = 1024; n0 = bx * 64;        roff = 0; }
        else if (bx < 20) { W = Wk; N = 256;  n0 = (bx - 16) * 64; roff = 1024; }
        else              { W = Wv; N = 256;  n0 = (bx - 20) * 64; roff = 1280; }
    } else {                    // ---- wtrans_one (Wo, 16 x 16)
        int wo = bid - 4480;
        int bx = wo % 16; k0 = (wo / 16) * 64;
        W = Wo; T = Two; N = 1024; n0 = bx * 64; roff = 0;
    }

#pragma unroll
    for (int it = 0; it < 4; it++) {
        int idx = tid + it * 256;
        int kk = idx >> 4, n4 = (idx & 15) * 4;
        float4 v = *(const float4*)(W + (size_t)(k0 + kk) * N + n0 + n4);
        Tl[kk][n4 + 0] = v.x; Tl[kk][n4 + 1] = v.y;
        Tl[kk][n4 + 2] = v.z; Tl[kk][n4 + 3] = v.w;
    }
    __syncthreads();
#pragma unroll
    for (int it = 0; it < 4; it++) {
        int idx = tid + it * 256;
        int n = idx >> 4, k4 = (idx & 15) * 4;
        ushort4 h4;
        h4.x = f2bf(Tl[k4 + 0][n]); h4.y = f2bf(Tl[k4 + 1][n]);
        h4.z = f2bf(Tl[k4 + 2][n]); h4.w = f2bf(Tl[k4 + 3][n]);
        *(ushort4*)(T + (size_t)(roff + n0 + n) * HIDDEN + k0 + k4) = h4;
    }
}

// ---------------------------------------------------------------------------
// Plain-bf16 MFMA GEMM, fp32 accumulate: C = A[M,K] @ B^T[N,K] + bias.
// R13: 64x128 tile (M x N), BK=64, XCD swizzle — OCCUPANCY round. R12's
// profile bounds every gemm dispatch <57us, implying ~200-270 TF — the 128^2
// tiles gave only 1-1.5 blocks/CU so the per-K-step barrier+vmcnt drain had
// NO cross-block overlap (m97's 874 TF ran ~4 blocks/CU). 64x128 => grids
// 768 (3/CU) / 512 (2/CU), LDS 24KB, acc 2x4 (~95 VGPR) => 5-6 blocks/CU
// capacity, all blocks co-resident. Per-element FP accumulation order is
// unchanged (same K-chunk sequence) -> absmax must stay 4.882812e-4.
// MODE 0: Q cols (bx<8) -> bf16 QKVb scaled 0.125*log2e; K/V cols (bx>=8)
// -> fused kvpack gather to Kf/Vf (re-derived for 64-row blocks: one kt
// tile, 2 heads per block). MODE 1: fp32 out.
// ---------------------------------------------------------------------------
template <int MODE>
__global__ __launch_bounds__(256)
void gemm_bf(const ushort* __restrict__ A, const ushort* __restrict__ Bt,
             const float* __restrict__ b0, const float* __restrict__ b1,
             const float* __restrict__ b2, void* __restrict__ Cout,
             ushort* __restrict__ Kf, ushort* __restrict__ Vf,
             int M, int N, int K)
{
    // smem 24KB: K-loop = Ah (64x64, 4096 ushorts) + Bh (128x64, 8192).
    // K/V epilogue reuses [0, 64*136) as a [64][136] bf16 tile (17,408 B).
    __shared__ __align__(16) ushort smem[12288];
    ushort* Ah = smem;
    ushort* Bh = smem + 64 * 64;

    const int tid = threadIdx.x;
    const int lane = tid & 63, wv = tid >> 6;
    const int wr = wv >> 1, wc = wv & 1;
    const int m = lane & 15, c = lane >> 4;

    // XCD-aware swizzle (bijective: nwg % 8 == 0 at both call sites)
    const int nwg = gridDim.x * gridDim.y;
    const int flat = blockIdx.y * gridDim.x + blockIdx.x;
    const int swz = (flat & 7) * (nwg >> 3) + (flat >> 3);
    const int bx = swz % gridDim.x, by = swz / gridDim.x;
    const int row0 = by * 64, col0 = bx * 128;

    // A staging: 2 slots/thread (64 rows x 64 cols); B: 4 slots (128 x 64).
    const ushort* gA[2]; int ldsA[2];
#pragma unroll
    for (int it = 0; it < 2; it++) {
        int idx = it * 256 + tid;
        gA[it] = A + (size_t)(row0 + (idx >> 3)) * K + (idx & 7) * 8;
        ldsA[it] = idx * 8;
    }
    const ushort* gB[4]; int ldsB[4];
#pragma unroll
    for (int it = 0; it < 4; it++) {
        int idx = it * 256 + tid;
        gB[it] = Bt + (size_t)(col0 + (idx >> 3)) * K + (idx & 7) * 8;
        ldsB[it] = idx * 8;
    }

    f32x4 acc[2][4];
#pragma unroll
    for (int t = 0; t < 2; t++)
#pragma unroll
        for (int u = 0; u < 4; u++) acc[t][u] = (f32x4){0.f, 0.f, 0.f, 0.f};

    for (int k0 = 0; k0 < K; k0 += 64) {
        __syncthreads();
#pragma unroll
        for (int it = 0; it < 2; it++) async16(gA[it] + k0, Ah + ldsA[it]);
#pragma unroll
        for (int it = 0; it < 4; it++) async16(gB[it] + k0, Bh + ldsB[it]);
        __syncthreads();   // compiler drains vmcnt before s_barrier

#pragma unroll
        for (int kk = 0; kk < 2; kk++) {
            s16x8 ah[2], bh[4];
#pragma unroll
            for (int t = 0; t < 2; t++)
                ah[t] = *(const s16x8*)&Ah[(wr * 32 + t * 16 + m) * 64 + kk * 32 + c * 8];
#pragma unroll
            for (int u = 0; u < 4; u++)
                bh[u] = *(const s16x8*)&Bh[(wc * 64 + u * 16 + m) * 64 + kk * 32 + c * 8];
#pragma unroll
            for (int t = 0; t < 2; t++)
#pragma unroll
                for (int u = 0; u < 4; u++)
                    acc[t][u] = __builtin_amdgcn_mfma_f32_16x16x32_bf16(ah[t], bh[u], acc[t][u], 0, 0, 0);
        }
    }

    const int orow = row0 + wr * 32 + 4 * c;   // + 16t + r  (t < 2)
    const int ocol = col0 + wc * 64 + m;       // + 16u

    if (MODE == 0 && bx >= 8) {
        // ---- fused kvpack: K blocks bx in {8,9}, V blocks in {10,11} ----
        // This block covers ONE kt tile (64 seq rows) x 2 heads.
        __syncthreads();   // all waves done reading Ah/Bh
#pragma unroll
        for (int u = 0; u < 4; u++) {
            int nloc = wc * 64 + m + 16 * u;
            int gn = col0 + nloc;
            float bias = (bx < 10) ? b1[gn - 1024] : b2[gn - 1280];
#pragma unroll
            for (int t = 0; t < 2; t++)
#pragma unroll
                for (int r = 0; r < 4; r++)
                    smem[(wr * 32 + 4 * c + 16 * t + r) * 136 + nloc] =
                        f2bf(acc[t][u][r] + bias);
        }
        __syncthreads();

        const int b_  = row0 >> 11;           // batch
        const int kt  = (row0 & 2047) >> 6;   // kt tile
        const int hk_base = (bx & 1) * 2;     // 8,10 -> hk {0,1}; 9,11 -> {2,3}

        if (bx < 10) {   // K gather (kvpack layout, 16 groups = 4 iters)
#pragma unroll
            for (int it = 0; it < 4; it++) {
                int idx = it * 256 + tid;
                int lane_ = idx & 63, grp = idx >> 6;
                int kc = grp & 3, t32 = (grp >> 2) & 1, hh = (grp >> 3) & 1;
                int n32_ = lane_ & 31, h5_ = lane_ >> 5;
                s16x8 fr = *(const s16x8*)&smem[(t32 * 32 + n32_) * 136
                                                + hh * 64 + kc * 16 + h5_ * 8];
                int hk = hk_base + hh;
                size_t flatK = ((size_t)(((b_ * NKV + hk) * 64 + kt * 2 + t32) * 4 + kc) * 64
                                + lane_) * 8;
                *(s16x8*)(Kf + flatK) = fr;
            }
        } else {         // V gather (column reads, 16 groups = 4 iters)
#pragma unroll
            for (int it = 0; it < 4; it++) {
                int idx = it * 256 + tid;
                int lane_ = idx & 63, grp = idx >> 6;
                int dn = grp & 1, kc = (grp >> 1) & 3, hh = (grp >> 3) & 1;
                int n32_ = lane_ & 31, h5_ = lane_ >> 5;
                s16x8 fr;
#pragma unroll
                for (int j = 0; j < 8; j++)
                    fr[j] = (short)smem[(kc * 16 + h5_ * 8 + j) * 136
                                        + hh * 64 + dn * 32 + n32_];
                int hk = hk_base + hh;
                size_t flatV = ((size_t)(((b_ * NKV + hk) * 32 + kt) * 8 + kc * 2 + dn) * 64
                                + lane_) * 8;
                *(s16x8*)(Vf + flatV) = fr;
            }
        }
        return;
    }

    if (MODE == 0) {
        // Q columns only (bx < 8): bf16 out, scaled 0.125*log2(e)
        ushort* Cb = (ushort*)Cout;
#pragma unroll
        for (int u = 0; u < 4; u++) {
            int n = ocol + 16 * u;
            float bias = b0[n];
#pragma unroll
            for (int t = 0; t < 2; t++)
#pragma unroll
                for (int r = 0; r < 4; r++)
                    Cb[(size_t)(orow + 16 * t + r) * N + n] =
                        f2bf((acc[t][u][r] + bias) * 0.18033688f);
        }
    } else {
        float* Cf = (float*)Cout;
#pragma unroll
        for (int u = 0; u < 4; u++) {
            int n = ocol + 16 * u;
            float bias = b0[n];
#pragma unroll
            for (int t = 0; t < 2; t++)
#pragma unroll
                for (int r = 0; r < 4; r++)
                    Cf[(size_t)(orow + 16 * t + r) * N + n] = acc[t][u][r] + bias;
        }
    }
}

// ---------------------------------------------------------------------------
// Flash attention v14 (FROZEN — measured best: 54.6 us fast-container, VGPR
// 84, LDS 33280): S^T QK + in-register P via cvtpk_rhu + permlane32_swap,
// f32-tree lsum, rotated load schedule. absmax 4.882812e-4.
// ---------------------------------------------------------------------------
__global__ __launch_bounds__(512, 2)
void attn_mfma14(const ushort* __restrict__ QKV, const ushort* __restrict__ Kf,
                 const ushort* __restrict__ Vf, ushort* __restrict__ Chi)
{
    __shared__ float OLb[4 * 32 * 64];   // 32,768 B merge buffer
    __shared__ float LLb[4 * 32];        // 512 B

    const int tid = threadIdx.x, w = tid >> 6, lane = tid & 63;
    const int g = w >> 2, ws_ = w & 3;               // q-group, kt-split index
    const int n32 = lane & 31, h5 = lane >> 5;
    const int h = blockIdx.y, b = blockIdx.z, hk = h >> 2;
    const int q0 = blockIdx.x * 64 + g * 32;

    // Q B-fragments (4 k-chunks of 16), hoisted
    const ushort* qrow = QKV + (size_t)(b * SEQ + q0 + n32) * NQKV + h * HDIM + h5 * 8;
    s16x8 aq[4];
#pragma unroll
    for (int kc = 0; kc < 4; kc++) aq[kc] = *(const s16x8*)(qrow + kc * 16);

    f32x16 accO[2];
#pragma unroll
    for (int j = 0; j < 16; j++) { accO[0][j] = 0.f; accO[1][j] = 0.f; }
    float lsum = 0.f;   // per-lane partial l[q=n32] over this lane's key slots

    const ushort* kf0 = Kf + (size_t)(b * NKV + hk) * (64 * 4 * 64 * 8) + (size_t)lane * 8;
    const ushort* vf0 = Vf + (size_t)(b * NKV + hk) * (32 * 8 * 64 * 8) + (size_t)lane * 8;

    s16x8 kreg[8], vreg[8], pa[4];

#define LOAD_K(kt_) do {                                                      \
    _Pragma("unroll")                                                         \
    for (int kn = 0; kn < 2; kn++)                                            \
        _Pragma("unroll")                                                     \
        for (int kc = 0; kc < 4; kc++)                                        \
            kreg[kn * 4 + kc] =                                               \
                *(const s16x8*)(kf0 + (size_t)(((kt_) * 2 + kn) * 4 + kc) * 512); \
} while (0)

#define LOAD_V(kt_) do {                                                      \
    _Pragma("unroll")                                                         \
    for (int kc = 0; kc < 4; kc++)                                            \
        _Pragma("unroll")                                                     \
        for (int dn = 0; dn < 2; dn++)                                        \
            vreg[kc * 2 + dn] =                                               \
                *(const s16x8*)(vf0 + (size_t)((kt_) * 8 + kc * 2 + dn) * 512); \
} while (0)

// S^T = K Q^T -> exp2 (log2e folded into Q) -> lsum f32 tree -> packed bf16
// P fragments built IN REGISTERS via cvtpk + permlane32_swap (no LDS).
#define QK_EXP_PACK() do {                                                    \
    _Pragma("unroll")                                                         \
    for (int kn = 0; kn < 2; kn++) {                                          \
        f32x16 S;                                                             \
        _Pragma("unroll")                                                     \
        for (int j = 0; j < 16; j++) S[j] = 0.f;                              \
        _Pragma("unroll")                                                     \
        for (int kc = 0; kc < 4; kc++)                                        \
            S = __builtin_amdgcn_mfma_f32_32x32x16_bf16(kreg[kn * 4 + kc],    \
                    aq[kc], S, 0, 0, 0);                                      \
        float p[16];                                                          \
        _Pragma("unroll")                                                     \
        for (int reg = 0; reg < 16; reg++) p[reg] = EXP2F(S[reg]);            \
        {                                                                     \
            float a0 = p[0] + p[1],   a1 = p[2] + p[3];                       \
            float a2 = p[4] + p[5],   a3 = p[6] + p[7];                       \
            float a4 = p[8] + p[9],   a5 = p[10] + p[11];                     \
            float a6 = p[12] + p[13], a7 = p[14] + p[15];                     \
            lsum += ((a0 + a1) + (a2 + a3)) + ((a4 + a5) + (a6 + a7));        \
        }                                                                     \
        {                                                                     \
            unsigned w0 = cvtpk2_rhu(p[0],  p[1]);   /* t0 w0 */              \
            unsigned w1 = cvtpk2_rhu(p[2],  p[3]);   /* t0 w1 */              \
            unsigned w2 = cvtpk2_rhu(p[4],  p[5]);   /* t1 w0 */              \
            unsigned w3 = cvtpk2_rhu(p[6],  p[7]);   /* t1 w1 */              \
            plane32_swap(w0, w2); plane32_swap(w1, w3);                       \
            union { s16x8 v; unsigned u[4]; } P0;                             \
            P0.u[0] = w0; P0.u[1] = w1; P0.u[2] = w2; P0.u[3] = w3;           \
            pa[kn * 2 + 0] = P0.v;                                            \
            unsigned w4 = cvtpk2_rhu(p[8],  p[9]);   /* t2 w0 */              \
            unsigned w5 = cvtpk2_rhu(p[10], p[11]);  /* t2 w1 */              \
            unsigned w6 = cvtpk2_rhu(p[12], p[13]);  /* t3 w0 */              \
            unsigned w7 = cvtpk2_rhu(p[14], p[15]);  /* t3 w1 */              \
            plane32_swap(w4, w6); plane32_swap(w5, w7);                       \
            union { s16x8 v; unsigned u[4]; } P1;                             \
            P1.u[0] = w4; P1.u[1] = w5; P1.u[2] = w6; P1.u[3] = w7;           \
            pa[kn * 2 + 1] = P1.v;                                            \
        }                                                                     \
    }                                                                         \
} while (0)

#define PV_STEP() do {                                                        \
    _Pragma("unroll")                                                         \
    for (int kc = 0; kc < 4; kc++) {                                          \
        _Pragma("unroll")                                                     \
        for (int dn = 0; dn < 2; dn++)                                        \
            accO[dn] = __builtin_amdgcn_mfma_f32_32x32x16_bf16(pa[kc],        \
                           vreg[kc * 2 + dn], accO[dn], 0, 0, 0);             \
    }                                                                         \
} while (0)

    // prologue: K0+V0 in flight; QK(t0) waits only K0 (V0 stays outstanding);
    // K1 issued right after QK consumed kreg.
    LOAD_K(ws_);
    LOAD_V(ws_);
    QK_EXP_PACK();
    LOAD_K(ws_ + 4);

#pragma unroll
    for (int i = 1; i < 8; i++) {
        PV_STEP();               // consumes pa(i-1) + vreg(i-1)
        LOAD_V(ws_ + 4 * i);     // V_i: cover = QK(i) below
        QK_EXP_PACK();           // waits K_i (oldest); overwrites pa (WAR ok)
        if (i < 7) LOAD_K(ws_ + 4 * (i + 1));   // K_{i+1}: cover = PV(i)
    }
    // epilogue: last tile's PV
    PV_STEP();

#undef LOAD_K
#undef LOAD_V
#undef QK_EXP_PACK
#undef PV_STEP

    // combine the two h5 halves of l[q=n32] (each lane then holds the full sum)
    lsum += __shfl_xor(lsum, 32, 64);

    const int qq = tid >> 4;          // 0..31
    const int d0 = (tid & 15) * 4;    // 0..60
#pragma unroll
    for (int phase = 0; phase < 2; phase++) {
        if (g == phase) {
#pragma unroll
            for (int reg = 0; reg < 16; reg++) {
                int q = (reg & 3) + 8 * (reg >> 2) + 4 * h5;
                OLb[(ws_ * 32 + q) * 64 + n32]      = accO[0][reg];
                OLb[(ws_ * 32 + q) * 64 + 32 + n32] = accO[1][reg];
            }
            if (h5 == 0) LLb[ws_ * 32 + n32] = lsum;
        }
        __syncthreads();
        {
            float lsum2 = LLb[qq] + LLb[32 + qq] + LLb[64 + qq] + LLb[96 + qq];
            float inv = 1.f / lsum2;
            ushort4 hs;
            float o0 = (OLb[(0 * 32 + qq) * 64 + d0 + 0] + OLb[(1 * 32 + qq) * 64 + d0 + 0] +
                        OLb[(2 * 32 + qq) * 64 + d0 + 0] + OLb[(3 * 32 + qq) * 64 + d0 + 0]) * inv;
            float o1 = (OLb[(0 * 32 + qq) * 64 + d0 + 1] + OLb[(1 * 32 + qq) * 64 + d0 + 1] +
                        OLb[(2 * 32 + qq) * 64 + d0 + 1] + OLb[(3 * 32 + qq) * 64 + d0 + 1]) * inv;
            float o2 = (OLb[(0 * 32 + qq) * 64 + d0 + 2] + OLb[(1 * 32 + qq) * 64 + d0 + 2] +
                        OLb[(2 * 32 + qq) * 64 + d0 + 2] + OLb[(3 * 32 + qq) * 64 + d0 + 2]) * inv;
            float o3 = (OLb[(0 * 32 + qq) * 64 + d0 + 3] + OLb[(1 * 32 + qq) * 64 + d0 + 3] +
                        OLb[(2 * 32 + qq) * 64 + d0 + 3] + OLb[(3 * 32 + qq) * 64 + d0 + 3]) * inv;
            hs.x = f2bf(o0); hs.y = f2bf(o1); hs.z = f2bf(o2); hs.w = f2bf(o3);
            size_t off = (size_t)(b * SEQ + blockIdx.x * 64 + phase * 32 + qq) * HIDDEN
                       + h * HDIM + d0;
            *(ushort4*)(Chi + off) = hs;
        }
        __syncthreads();   // before next phase overwrites merge buffers
    }
}

// ---------------------------------------------------------------------------
extern "C" void kernel_launch(void* const* d_in, const int* in_sizes, int n_in,
                              void* d_out, int out_size, void* d_ws, size_t ws_size,
                              hipStream_t stream)
{
    const float* X  = (const float*)d_in[0];
    const float* Wq = (const float*)d_in[1];
    const float* bq = (const float*)d_in[2];
    const float* Wk = (const float*)d_in[3];
    const float* bk = (const float*)d_in[4];
    const float* Wv = (const float*)d_in[5];
    const float* bv = (const float*)d_in[6];
    const float* Wo = (const float*)d_in[7];
    const float* bo = (const float*)d_in[8];
    float* out = (float*)d_out;

    const int M = BATCH * SEQ;  // 4096
    // ws layout (37 MB): Xb 8 | Ctx 8 | QKVb 12 | Wqkvt 3 | Wot 2 | Kf 2 | Vf 2
    char* ws = (char*)d_ws;
    ushort* Xb    = (ushort*)(ws);
    ushort* Ctx   = (ushort*)(ws + (8u  << 20));
    ushort* QKVb  = (ushort*)(ws + (16u << 20));
    ushort* Wqkvt = (ushort*)(ws + (28u << 20));
    ushort* Wot   = (ushort*)(ws + (31u << 20));
    ushort* Kf    = (ushort*)(ws + (33u << 20));
    ushort* Vf    = (ushort*)(ws + (35u << 20));

    prep<<<dim3(4736), 256, 0, stream>>>(X, Xb, Wq, Wk, Wv, Wqkvt, Wo, Wot);

    // gemm0 produces Q (QKVb cols 0-1023) + Kf/Vf directly (fused kvpack)
    gemm_bf<0><<<dim3(NQKV / 128, M / 64), 256, 0, stream>>>(
        Xb, Wqkvt, bq, bk, bv, (void*)QKVb, Kf, Vf, M, NQKV, HIDDEN);

    attn_mfma14<<<dim3(SEQ / 64, NHEAD, BATCH), 512, 0, stream>>>(QKVb, Kf, Vf, Ctx);

    gemm_bf<1><<<dim3(HIDDEN / 128, M / 64), 256, 0, stream>>>(
        Ctx, Wot, bo, nullptr, nullptr, (void*)out, nullptr, nullptr,
        M, HIDDEN, HIDDEN);
}